// Round 2
// baseline (1564.638 us; speedup 1.0000x reference)
//
#include <hip/hip_runtime.h>
#include <cmath>

// Problem constants
#define NH    12
#define T     1024
#define ROWS  4096      // B*T
#define NE    768
#define KP1   784       // pad for K=769 / K=780 (multiple of 16)
#define KP2   3088      // pad for K=3076
#define NEXP  3136      // padded expand N (3075 -> 49*64)
#define HEXP  3075

// ---------------- reduction helpers ----------------
__device__ __forceinline__ float blk_reduce_sum(float v, float* sm) {
  #pragma unroll
  for (int o = 32; o > 0; o >>= 1) v += __shfl_xor(v, o, 64);
  int lane = threadIdx.x & 63, w = threadIdx.x >> 6;
  __syncthreads();
  if (lane == 0) sm[w] = v;
  __syncthreads();
  return sm[0] + sm[1] + sm[2] + sm[3];
}
__device__ __forceinline__ float red16_sum(float v) {
  #pragma unroll
  for (int o = 1; o < 16; o <<= 1) v += __shfl_xor(v, o, 64);
  return v;
}
__device__ __forceinline__ float red16_max(float v) {
  #pragma unroll
  for (int o = 1; o < 16; o <<= 1) v = fmaxf(v, __shfl_xor(v, o, 64));
  return v;
}

// ---------------- weight pad-copy ----------------
__global__ void copy_pad(float* __restrict__ dst, const float* __restrict__ src,
                         int rows, int srcK, int dstK, int rowsPad) {
  int idx = blockIdx.x * 256 + threadIdx.x;
  int total = rowsPad * dstK;
  if (idx >= total) return;
  int r = idx / dstK, c = idx - r * dstK;
  dst[idx] = (r < rows && c < srcK) ? src[(size_t)r * srcK + c] : 0.f;
}

__global__ void zero_aout_pad(float* __restrict__ aoutb) {
  int r = blockIdx.x * 256 + threadIdx.x;
  if (r < ROWS) {
    float4 z = make_float4(0.f, 0.f, 0.f, 0.f);
    *(float4*)&aoutb[(size_t)r * KP1 + 780] = z;
  }
}

// ---------------- layernorm + hyperboloid project ----------------
// out row (stride KP1): [0]=sqrt(exp(curv)+|y|^2), [1..768]=y, [769..783]=0
__global__ __launch_bounds__(256) void ln_project(
    const float* __restrict__ xin, const float* __restrict__ g,
    const float* __restrict__ bb, const float* __restrict__ curv,
    float* __restrict__ outp) {
  __shared__ float sm[4];
  const int row = blockIdx.x;
  const int tid = threadIdx.x;
  const float* xr = xin + (size_t)row * NE;
  float xv[3];
  float s = 0.f, ss = 0.f;
  #pragma unroll
  for (int i = 0; i < 3; ++i) {
    xv[i] = xr[tid + 256 * i];
    s += xv[i]; ss += xv[i] * xv[i];
  }
  s = blk_reduce_sum(s, sm);
  ss = blk_reduce_sum(ss, sm);
  float mean = s * (1.f / 768.f);
  float var = ss * (1.f / 768.f) - mean * mean;
  float rstd = rsqrtf(var + 1e-5f);
  float yv[3]; float ys = 0.f;
  #pragma unroll
  for (int i = 0; i < 3; ++i) {
    int c = tid + 256 * i;
    yv[i] = (xv[i] - mean) * rstd * g[c] + bb[c];
    ys += yv[i] * yv[i];
  }
  ys = blk_reduce_sum(ys, sm);
  float tc = sqrtf(expf(curv[0]) + ys);
  float* orow = outp + (size_t)row * KP1;
  #pragma unroll
  for (int i = 0; i < 3; ++i) orow[1 + tid + 256 * i] = yv[i];
  if (tid == 0) orow[0] = tc;
  if (tid < KP1 - 769) orow[769 + tid] = 0.f;
}

// ---------------- generic NT GEMM: C[r,c] = sum_k A[r,k]*W[c,k] (+bias,+res) ----
__global__ __launch_bounds__(256) void gemm_nt(
    const float* __restrict__ A, int lda,
    const float* __restrict__ W, int ldw,
    float* __restrict__ C, int ldc,
    int nk, const float* __restrict__ bias, int biasN,
    const float* __restrict__ res, int ldres) {
  __shared__ float As[16][64];
  __shared__ float Ws[16][64];
  const int tid = threadIdx.x;
  const int tx = tid & 15, ty = tid >> 4;
  const int lrow = tid >> 2, lp = tid & 3;
  const int rowBase = blockIdx.y << 6;
  const int colBase = blockIdx.x << 6;
  const float* Ap = A + (size_t)(rowBase + lrow) * lda + lp * 4;
  const float* Wp = W + (size_t)(colBase + lrow) * ldw + lp * 4;
  float acc[4][4] = {};
  for (int kt = 0; kt < nk; ++kt) {
    float4 av = *(const float4*)Ap;
    float4 wv = *(const float4*)Wp;
    Ap += 16; Wp += 16;
    __syncthreads();
    As[lp * 4 + 0][lrow] = av.x; As[lp * 4 + 1][lrow] = av.y;
    As[lp * 4 + 2][lrow] = av.z; As[lp * 4 + 3][lrow] = av.w;
    Ws[lp * 4 + 0][lrow] = wv.x; Ws[lp * 4 + 1][lrow] = wv.y;
    Ws[lp * 4 + 2][lrow] = wv.z; Ws[lp * 4 + 3][lrow] = wv.w;
    __syncthreads();
    #pragma unroll
    for (int kk = 0; kk < 16; ++kk) {
      float4 a4 = *(const float4*)&As[kk][ty * 4];
      float4 w4 = *(const float4*)&Ws[kk][tx * 4];
      float aa[4] = {a4.x, a4.y, a4.z, a4.w};
      float ww[4] = {w4.x, w4.y, w4.z, w4.w};
      #pragma unroll
      for (int i = 0; i < 4; ++i)
        #pragma unroll
        for (int j = 0; j < 4; ++j)
          acc[i][j] = fmaf(aa[i], ww[j], acc[i][j]);
    }
  }
  #pragma unroll
  for (int i = 0; i < 4; ++i) {
    const int r = rowBase + ty * 4 + i;
    const int c0 = colBase + tx * 4;
    float o[4];
    #pragma unroll
    for (int j = 0; j < 4; ++j) o[j] = acc[i][j];
    if (bias) {
      #pragma unroll
      for (int j = 0; j < 4; ++j) { int c = c0 + j; o[j] += (c < biasN) ? bias[c] : 0.f; }
    }
    if (res) {
      #pragma unroll
      for (int j = 0; j < 4; ++j) o[j] += res[(size_t)r * ldres + c0 + j];
    }
    *(float4*)&C[(size_t)r * ldc + c0] = make_float4(o[0], o[1], o[2], o[3]);
  }
}

// ---------------- rotary + per-head hyperboloid project ----------------
__global__ __launch_bounds__(256) void rope_project(
    const float* __restrict__ qkv, const float* __restrict__ ac,
    float* __restrict__ qs, float* __restrict__ ks, float* __restrict__ vs,
    float* __restrict__ q0, float* __restrict__ k0, float* __restrict__ v0) {
  int gid = blockIdx.x * 4 + (threadIdx.x >> 6);
  int lane = threadIdx.x & 63;
  int h = gid % NH;
  int bt = gid / NH;
  int t = bt & (T - 1);
  int b = bt >> 10;
  size_t base = (size_t)bt * 2304 + h * 64;
  float qv = qkv[base + lane];
  float kv = qkv[base + 768 + lane];
  float vv = qkv[base + 1536 + lane];
  int f = lane & 31;
  float ang = (float)t * powf(10000.f, -(float)f * (1.f / 32.f));
  float sn, cs;
  sincosf(ang, &sn, &cs);
  float qp = __shfl(qv, lane ^ 32, 64);
  float kp = __shfl(kv, lane ^ 32, 64);
  float qr = (lane < 32) ? (qv * cs + qp * sn) : (-qp * sn + qv * cs);
  float kr = (lane < 32) ? (kv * cs + kp * sn) : (-kp * sn + kv * cs);
  float Kh = expf(ac[h]);
  float sq = qr * qr, sk = kr * kr, sv = vv * vv;
  #pragma unroll
  for (int o = 32; o > 0; o >>= 1) {
    sq += __shfl_xor(sq, o, 64);
    sk += __shfl_xor(sk, o, 64);
    sv += __shfl_xor(sv, o, 64);
  }
  size_t idx = ((size_t)(b * NH + h) * T + t);
  qs[idx * 64 + lane] = qr;
  ks[idx * 64 + lane] = kr;
  vs[idx * 64 + lane] = vv;
  if (lane == 0) {
    q0[idx] = sqrtf(Kh + sq);
    k0[idx] = sqrtf(Kh + sk);
    v0[idx] = sqrtf(Kh + sv);
  }
}

// ---------------- flash Lorentz-distance attention ----------------
// one block per (q-tile of 64, b*h). score = -sqrtK*arccosh(max((q0k0 - qs.ks)/K, 1+eps))
__global__ __launch_bounds__(256) void attn_kernel(
    const float* __restrict__ qs, const float* __restrict__ ks, const float* __restrict__ vs,
    const float* __restrict__ q0, const float* __restrict__ k0, const float* __restrict__ v0,
    const float* __restrict__ ac, float* __restrict__ aout) {
  __shared__ float Qs[64][76];
  __shared__ float KPs[64][76];   // K tile during score phase, then P tile
  __shared__ float Vs[64][76];
  __shared__ float q0s[64], k0s[64], v0s[64];

  const int bh = blockIdx.y;
  const int h = bh % NH;
  const int b = bh / NH;
  const int qtile = (int)gridDim.x - 1 - (int)blockIdx.x;  // heavy blocks first
  const int qt0 = qtile * 64;
  const int tid = threadIdx.x;
  const int tx = tid & 15, ty = tid >> 4;
  const int lr = tid >> 4;        // 0..15 (tile-load row base)
  const int lc = (tid & 15) * 4;  // 0..60 (tile-load col)

  const float Kh = expf(ac[h]);
  const float sqrtK = sqrtf(Kh);
  const float invK = 1.0f / Kh;

  {
    // full 64x64 Q tile: 4 float4 per thread
    #pragma unroll
    for (int rr = 0; rr < 4; ++rr) {
      int row = lr + 16 * rr;
      *(float4*)&Qs[row][lc] =
          *(const float4*)&qs[((size_t)bh * T + qt0 + row) * 64 + lc];
    }
    if (tid < 64) q0s[tid] = q0[(size_t)bh * T + qt0 + tid];
  }

  float m[4], l[4], a0acc[4], acc[4][4];
  #pragma unroll
  for (int ii = 0; ii < 4; ++ii) {
    m[ii] = -__builtin_inff();
    l[ii] = 0.f; a0acc[ii] = 0.f;
    #pragma unroll
    for (int dd = 0; dd < 4; ++dd) acc[ii][dd] = 0.f;
  }

  const int ntiles = qtile + 1;
  for (int kt = 0; kt < ntiles; ++kt) {
    const int j0 = kt * 64;
    __syncthreads();
    {
      // full 64x64 K and V tiles
      #pragma unroll
      for (int rr = 0; rr < 4; ++rr) {
        int row = lr + 16 * rr;
        size_t src = ((size_t)bh * T + j0 + row) * 64 + lc;
        *(float4*)&KPs[row][lc] = *(const float4*)&ks[src];
        *(float4*)&Vs[row][lc] = *(const float4*)&vs[src];
      }
      if (tid < 64) {
        k0s[tid] = k0[(size_t)bh * T + j0 + tid];
        v0s[tid] = v0[(size_t)bh * T + j0 + tid];
      }
    }
    __syncthreads();

    float dot[4][4] = {};
    for (int d4 = 0; d4 < 16; ++d4) {
      float4 qv[4], kv[4];
      #pragma unroll
      for (int ii = 0; ii < 4; ++ii) qv[ii] = *(const float4*)&Qs[4 * ty + ii][4 * d4];
      #pragma unroll
      for (int jj = 0; jj < 4; ++jj) kv[jj] = *(const float4*)&KPs[16 * jj + tx][4 * d4];
      #pragma unroll
      for (int ii = 0; ii < 4; ++ii)
        #pragma unroll
        for (int jj = 0; jj < 4; ++jj)
          dot[ii][jj] += qv[ii].x * kv[jj].x + qv[ii].y * kv[jj].y
                       + qv[ii].z * kv[jj].z + qv[ii].w * kv[jj].w;
    }
    __syncthreads();  // all K reads from KPs done before P overwrites it

    float alpha[4];
    #pragma unroll
    for (int ii = 0; ii < 4; ++ii) {
      const int i = qt0 + 4 * ty + ii;
      const float q0v = q0s[4 * ty + ii];
      float sc[4];
      float rowm = -__builtin_inff();
      #pragma unroll
      for (int jj = 0; jj < 4; ++jj) {
        const int jl = 16 * jj + tx;
        const int j = j0 + jl;
        float cc = (q0v * k0s[jl] - dot[ii][jj]) * invK;
        float u = fmaxf(cc - 1.f, 1e-6f);
        // arccosh(1+u) = log1p(u + sqrt(u*(u+2))) — cancellation-free
        float dist = sqrtK * log1pf(u + sqrtf(u * (u + 2.f)));
        sc[jj] = (j <= i) ? -dist : -__builtin_inff();
        rowm = fmaxf(rowm, sc[jj]);
      }
      rowm = red16_max(rowm);
      const float mnew = fmaxf(m[ii], rowm);
      alpha[ii] = __expf(m[ii] - mnew);
      m[ii] = mnew;
      float ls = 0.f, a0s = 0.f;
      #pragma unroll
      for (int jj = 0; jj < 4; ++jj) {
        const float pv = __expf(sc[jj] - mnew);
        KPs[4 * ty + ii][16 * jj + tx] = pv;
        ls += pv;
        a0s += pv * v0s[16 * jj + tx];
      }
      l[ii] = l[ii] * alpha[ii] + ls;
      a0acc[ii] = a0acc[ii] * alpha[ii] + a0s;
    }
    __syncthreads();  // P visible to all

    #pragma unroll
    for (int ii = 0; ii < 4; ++ii)
      #pragma unroll
      for (int dd = 0; dd < 4; ++dd) acc[ii][dd] *= alpha[ii];

    for (int j4 = 0; j4 < 16; ++j4) {
      float4 vr0 = *(const float4*)&Vs[4 * j4 + 0][4 * tx];
      float4 vr1 = *(const float4*)&Vs[4 * j4 + 1][4 * tx];
      float4 vr2 = *(const float4*)&Vs[4 * j4 + 2][4 * tx];
      float4 vr3 = *(const float4*)&Vs[4 * j4 + 3][4 * tx];
      #pragma unroll
      for (int ii = 0; ii < 4; ++ii) {
        float4 pv = *(const float4*)&KPs[4 * ty + ii][4 * j4];
        acc[ii][0] += pv.x * vr0.x + pv.y * vr1.x + pv.z * vr2.x + pv.w * vr3.x;
        acc[ii][1] += pv.x * vr0.y + pv.y * vr1.y + pv.z * vr2.y + pv.w * vr3.y;
        acc[ii][2] += pv.x * vr0.z + pv.y * vr1.z + pv.z * vr2.z + pv.w * vr3.z;
        acc[ii][3] += pv.x * vr0.w + pv.y * vr1.w + pv.z * vr2.w + pv.w * vr3.w;
      }
    }
  }

  #pragma unroll
  for (int ii = 0; ii < 4; ++ii) {
    float lf = red16_sum(l[ii]);
    float a0f = red16_sum(a0acc[ii]);
    const float invl = 1.f / lf;
    float av[4]; float ssq = 0.f;
    #pragma unroll
    for (int dd = 0; dd < 4; ++dd) { av[dd] = acc[ii][dd] * invl; ssq += av[dd] * av[dd]; }
    ssq = red16_sum(ssq);
    const float a0n = a0f * invl;
    const float nsq = fmaxf(a0n * a0n - ssq, 1e-6f);
    const float scale = sqrtK * rsqrtf(nsq);
    const int i = qt0 + 4 * ty + ii;
    float* orow = aout + (size_t)(b * T + i) * KP1 + h * 65;
    #pragma unroll
    for (int dd = 0; dd < 4; ++dd) orow[1 + 4 * tx + dd] = av[dd] * scale;
    if (tx == 0) orow[0] = a0n * scale;
  }
}

// ---------------- exact gelu + project (MLP middle) ----------------
__global__ __launch_bounds__(256) void gelu_project(
    const float* __restrict__ hsrc, const float* __restrict__ curv, float* __restrict__ hp) {
  __shared__ float sm[4];
  const int row = blockIdx.x;
  const int tid = threadIdx.x;
  const float* hr = hsrc + (size_t)row * NEXP;
  float gv[13];
  float ss = 0.f;
  #pragma unroll
  for (int i = 0; i < 13; ++i) {
    int c = tid + 256 * i;
    float xx = (c < HEXP) ? hr[c] : 0.f;
    float gg = 0.5f * xx * (1.f + erff(xx * 0.70710678118654752f));
    gv[i] = gg; ss += gg * gg;
  }
  ss = blk_reduce_sum(ss, sm);
  float tc = sqrtf(expf(curv[0]) + ss);
  float* orow = hp + (size_t)row * KP2;
  #pragma unroll
  for (int i = 0; i < 13; ++i) {
    int c = tid + 256 * i;
    if (c < HEXP) orow[1 + c] = gv[i];
  }
  if (tid == 0) orow[0] = tc;
  if (tid < KP2 - (HEXP + 1)) orow[HEXP + 1 + tid] = 0.f;
}

// ---------------- final projection into d_out (stride 769) ----------------
__global__ __launch_bounds__(256) void final_project(
    const float* __restrict__ x3, const float* __restrict__ curv, float* __restrict__ out) {
  __shared__ float sm[4];
  const int row = blockIdx.x;
  const int tid = threadIdx.x;
  const float* xr = x3 + (size_t)row * NE;
  float v[3]; float ss = 0.f;
  #pragma unroll
  for (int i = 0; i < 3; ++i) { v[i] = xr[tid + 256 * i]; ss += v[i] * v[i]; }
  ss = blk_reduce_sum(ss, sm);
  float tc = sqrtf(expf(curv[0]) + ss);
  float* o = out + (size_t)row * 769;
  #pragma unroll
  for (int i = 0; i < 3; ++i) o[1 + tid + 256 * i] = v[i];
  if (tid == 0) o[0] = tc;
}

// ---------------- launcher ----------------
// Workspace budget: 42,300,416 floats = ~169.2 MB (buffer lifetimes unioned).
extern "C" void kernel_launch(void* const* d_in, const int* in_sizes, int n_in,
                              void* d_out, int out_size, void* d_ws, size_t ws_size,
                              hipStream_t stream) {
  (void)in_sizes; (void)n_in; (void)out_size; (void)ws_size;
  const float* x     = (const float*)d_in[0];
  const float* bc    = (const float*)d_in[1];
  const float* mc    = (const float*)d_in[2];
  const float* ac    = (const float*)d_in[3];
  const float* qkvw  = (const float*)d_in[4];
  const float* projw = (const float*)d_in[5];
  const float* projb = (const float*)d_in[6];
  const float* expw  = (const float*)d_in[7];
  const float* expb  = (const float*)d_in[8];
  const float* shrw  = (const float*)d_in[9];
  const float* shrb  = (const float*)d_in[10];
  const float* lng   = (const float*)d_in[11];
  const float* lnb   = (const float*)d_in[12];
  float* out = (float*)d_out;

  float* W = (float*)d_ws;
  float* qkv_wp = W;
  float* proj_wp = qkv_wp + (size_t)2304 * KP1;
  float* exp_wp  = proj_wp + (size_t)768 * KP1;
  float* shr_wp  = exp_wp + (size_t)NEXP * KP1;
  float* lnp     = shr_wp + (size_t)768 * KP2;
  float* aoutb   = lnp + (size_t)ROWS * KP1;
  float* x2      = aoutb + (size_t)ROWS * KP1;
  float* r2      = x2 + (size_t)ROWS * NE;
  // region r2 union #1: qkv + q/k/v tensors (dead after attention)
  float* qkvb = r2;
  float* qsb  = qkvb + (size_t)ROWS * 2304;
  float* ksb  = qsb + (size_t)48 * T * 64;
  float* vsb  = ksb + (size_t)48 * T * 64;
  float* q0b  = vsb + (size_t)48 * T * 64;
  float* k0b  = q0b + (size_t)48 * T;
  float* v0b  = k0b + (size_t)48 * T;
  // region r2 union #2: mlp h + projected h
  float* hbuf = r2;
  float* hp   = r2 + (size_t)ROWS * NEXP;

  // weight padding (must rerun every call: ws re-poisoned)
  copy_pad<<<(2304 * KP1 + 255) / 256, 256, 0, stream>>>(qkv_wp, qkvw, 2304, 769, KP1, 2304);
  copy_pad<<<(768 * KP1 + 255) / 256, 256, 0, stream>>>(proj_wp, projw, 768, 780, KP1, 768);
  copy_pad<<<(NEXP * KP1 + 255) / 256, 256, 0, stream>>>(exp_wp, expw, HEXP, 769, KP1, NEXP);
  copy_pad<<<(768 * KP2 + 255) / 256, 256, 0, stream>>>(shr_wp, shrw, 768, 3076, KP2, 768);
  zero_aout_pad<<<(ROWS + 255) / 256, 256, 0, stream>>>(aoutb);

  // 1. block_norm(lx)  (ln over x, project)
  ln_project<<<ROWS, 256, 0, stream>>>(x, lng, lnb, bc, lnp);
  // 2. qkv = ln1p @ qkv_w^T
  gemm_nt<<<dim3(2304 / 64, ROWS / 64), 256, 0, stream>>>(
      lnp, KP1, qkv_wp, KP1, qkvb, 2304, KP1 / 16, nullptr, 0, nullptr, 0);
  // 3. rotary + per-head project
  rope_project<<<(ROWS * NH) / 4, 256, 0, stream>>>(qkvb, ac, qsb, ksb, vsb, q0b, k0b, v0b);
  // 4. Lorentz flash attention
  attn_kernel<<<dim3(T / 64, 48), 256, 0, stream>>>(qsb, ksb, vsb, q0b, k0b, v0b, ac, aoutb);
  // 5. attn proj + bias + residual(x) -> x2
  gemm_nt<<<dim3(768 / 64, ROWS / 64), 256, 0, stream>>>(
      aoutb, KP1, proj_wp, KP1, x2, NE, KP1 / 16, projb, 768, x, NE);
  // 6. block_norm(lx) #2
  ln_project<<<ROWS, 256, 0, stream>>>(x2, lng, lnb, bc, lnp);
  // 7. mlp expand + bias
  gemm_nt<<<dim3(NEXP / 64, ROWS / 64), 256, 0, stream>>>(
      lnp, KP1, exp_wp, KP1, hbuf, NEXP, KP1 / 16, expb, HEXP, nullptr, 0);
  // 8. gelu + project
  gelu_project<<<ROWS, 256, 0, stream>>>(hbuf, mc, hp);
  // 9. mlp shrink + bias + residual(x2) -> x2 (in-place, element-wise safe)
  gemm_nt<<<dim3(768 / 64, ROWS / 64), 256, 0, stream>>>(
      hp, KP2, shr_wp, KP2, x2, NE, KP2 / 16, shrb, 768, x2, NE);
  // 10. final project -> out
  final_project<<<ROWS, 256, 0, stream>>>(x2, bc, out);
}

// Round 3
// 853.657 us; speedup vs baseline: 1.8329x; 1.8329x over previous
//
#include <hip/hip_runtime.h>
#include <cmath>

typedef unsigned short ushort_t;
typedef __attribute__((ext_vector_type(8))) short short8;
typedef __attribute__((ext_vector_type(4))) float floatx4;

// Problem constants
#define NH    12
#define T     1024
#define ROWS  4096      // B*T
#define NE    768
#define KPA   800       // bf16 K-pad for 769/780 (multiple of 32)
#define KPB   3104      // bf16 K-pad for 3076
#define NEXP  3200      // padded expand N (3075 -> 25*128)
#define HEXP  3075

// ---------------- helpers ----------------
__device__ __forceinline__ ushort_t f2bf(float f) {
  union { float f; unsigned u; } v; v.f = f;
  unsigned r = v.u + 0x7fffu + ((v.u >> 16) & 1u);
  return (ushort_t)(r >> 16);
}
__device__ __forceinline__ float blk_reduce_sum(float v, float* sm) {
  #pragma unroll
  for (int o = 32; o > 0; o >>= 1) v += __shfl_xor(v, o, 64);
  int lane = threadIdx.x & 63, w = threadIdx.x >> 6;
  __syncthreads();
  if (lane == 0) sm[w] = v;
  __syncthreads();
  return sm[0] + sm[1] + sm[2] + sm[3];
}
__device__ __forceinline__ float red16_sum(float v) {
  #pragma unroll
  for (int o = 1; o < 16; o <<= 1) v += __shfl_xor(v, o, 64);
  return v;
}
__device__ __forceinline__ float red16_max(float v) {
  #pragma unroll
  for (int o = 1; o < 16; o <<= 1) v = fmaxf(v, __shfl_xor(v, o, 64));
  return v;
}

// ---------------- weight pad-convert fp32 -> bf16 ----------------
__global__ void cvt_pad(ushort_t* __restrict__ dst, const float* __restrict__ src,
                        int rows, int srcK, int dstK, int rowsPad) {
  int idx = blockIdx.x * 256 + threadIdx.x;
  int total = rowsPad * dstK;
  if (idx >= total) return;
  int r = idx / dstK, c = idx - r * dstK;
  dst[idx] = (r < rows && c < srcK) ? f2bf(src[(size_t)r * srcK + c]) : (ushort_t)0;
}

__global__ void zero_aout_pad(float* __restrict__ aoutf) {
  int r = blockIdx.x * 256 + threadIdx.x;
  if (r < ROWS) {
    float4 z = make_float4(0.f, 0.f, 0.f, 0.f);
    #pragma unroll
    for (int j = 0; j < 5; ++j)
      *(float4*)&aoutf[(size_t)r * KPA + 780 + 4 * j] = z;
  }
}

// ---------------- layernorm + hyperboloid project -> bf16 (stride KPA) -------
__global__ __launch_bounds__(256) void ln_project(
    const float* __restrict__ xin, const float* __restrict__ g,
    const float* __restrict__ bb, const float* __restrict__ curv,
    ushort_t* __restrict__ outp) {
  __shared__ float sm[4];
  const int row = blockIdx.x;
  const int tid = threadIdx.x;
  const float* xr = xin + (size_t)row * NE;
  float xv[3];
  float s = 0.f, ss = 0.f;
  #pragma unroll
  for (int i = 0; i < 3; ++i) {
    xv[i] = xr[tid + 256 * i];
    s += xv[i]; ss += xv[i] * xv[i];
  }
  s = blk_reduce_sum(s, sm);
  ss = blk_reduce_sum(ss, sm);
  float mean = s * (1.f / 768.f);
  float var = ss * (1.f / 768.f) - mean * mean;
  float rstd = rsqrtf(var + 1e-5f);
  float yv[3]; float ys = 0.f;
  #pragma unroll
  for (int i = 0; i < 3; ++i) {
    int c = tid + 256 * i;
    yv[i] = (xv[i] - mean) * rstd * g[c] + bb[c];
    ys += yv[i] * yv[i];
  }
  ys = blk_reduce_sum(ys, sm);
  float tc = sqrtf(expf(curv[0]) + ys);
  ushort_t* orow = outp + (size_t)row * KPA;
  #pragma unroll
  for (int i = 0; i < 3; ++i) orow[1 + tid + 256 * i] = f2bf(yv[i]);
  if (tid == 0) orow[0] = f2bf(tc);
  if (tid < KPA - 769) orow[769 + tid] = 0;
}

// ---------------- bf16 MFMA NT GEMM (m97 structure) --------------------------
// C[r,c] = sum_k A[r,k]*W[c,k] (+bias,+res), 128x128 tile, BK=32
__global__ __launch_bounds__(256) void gemm_bf16(
    const ushort_t* __restrict__ A, int lda,
    const ushort_t* __restrict__ W, int ldw,
    float* __restrict__ C, int ldc,
    int nk, const float* __restrict__ bias, int biasN,
    const float* __restrict__ res, int ldres) {
  __shared__ ushort_t As[128 * 32];
  __shared__ ushort_t Bs[128 * 32];
  const int tid = threadIdx.x;
  const int w = tid >> 6, lane = tid & 63;
  const int rowBase = (int)blockIdx.y << 7;
  const int colBase = (int)blockIdx.x << 7;
  const int wm = (w & 1) * 64, wn = (w >> 1) * 64;
  const int lm = lane & 15, quad = lane >> 4;

  floatx4 acc[4][4];
  #pragma unroll
  for (int i = 0; i < 4; ++i)
    #pragma unroll
    for (int j = 0; j < 4; ++j) {
      floatx4 z = {0.f, 0.f, 0.f, 0.f};
      acc[i][j] = z;
    }

  for (int kt = 0; kt < nk; ++kt) {
    __syncthreads();   // prior ds_reads done before overwrite
    #pragma unroll
    for (int j = 0; j < 2; ++j) {
      int c = w * 128 + j * 64 + lane;
      int r = c >> 2, c8 = c & 3;
      const ushort_t* ga = A + (size_t)(rowBase + r) * lda + kt * 32 + c8 * 8;
      const ushort_t* gb = W + (size_t)(colBase + r) * ldw + kt * 32 + c8 * 8;
      __builtin_amdgcn_global_load_lds(
          (const __attribute__((address_space(1))) void*)ga,
          (__attribute__((address_space(3))) void*)&As[(w * 128 + j * 64) * 8],
          16, 0, 0);
      __builtin_amdgcn_global_load_lds(
          (const __attribute__((address_space(1))) void*)gb,
          (__attribute__((address_space(3))) void*)&Bs[(w * 128 + j * 64) * 8],
          16, 0, 0);
    }
    __syncthreads();   // drains vmcnt: LDS tiles visible

    short8 af[4], bfr[4];
    #pragma unroll
    for (int i = 0; i < 4; ++i) {
      af[i]  = *(const short8*)&As[(wm + i * 16 + lm) * 32 + quad * 8];
      bfr[i] = *(const short8*)&Bs[(wn + i * 16 + lm) * 32 + quad * 8];
    }
    #pragma unroll
    for (int i = 0; i < 4; ++i)
      #pragma unroll
      for (int jn = 0; jn < 4; ++jn)
        acc[i][jn] = __builtin_amdgcn_mfma_f32_16x16x32_bf16(
            af[i], bfr[jn], acc[i][jn], 0, 0, 0);
  }

  // epilogue: C/D layout col=lane&15, row=quad*4+reg
  #pragma unroll
  for (int i = 0; i < 4; ++i) {
    #pragma unroll
    for (int jn = 0; jn < 4; ++jn) {
      const int col = colBase + wn + jn * 16 + lm;
      #pragma unroll
      for (int rg = 0; rg < 4; ++rg) {
        const int row = rowBase + wm + i * 16 + quad * 4 + rg;
        float o = acc[i][jn][rg];
        if (bias) o += (col < biasN) ? bias[col] : 0.f;
        if (res) o += res[(size_t)row * ldres + col];
        C[(size_t)row * ldc + col] = o;
      }
    }
  }
}

// ---------------- rotary + per-head hyperboloid project ----------------
__global__ __launch_bounds__(256) void rope_project(
    const float* __restrict__ qkv, const float* __restrict__ ac,
    float* __restrict__ qs, float* __restrict__ ks, float* __restrict__ vs,
    float* __restrict__ q0, float* __restrict__ k0, float* __restrict__ v0) {
  int gid = blockIdx.x * 4 + (threadIdx.x >> 6);
  int lane = threadIdx.x & 63;
  int h = gid % NH;
  int bt = gid / NH;
  int t = bt & (T - 1);
  int b = bt >> 10;
  size_t base = (size_t)bt * 2304 + h * 64;
  float qv = qkv[base + lane];
  float kv = qkv[base + 768 + lane];
  float vv = qkv[base + 1536 + lane];
  int f = lane & 31;
  float ang = (float)t * powf(10000.f, -(float)f * (1.f / 32.f));
  float sn, cs;
  sincosf(ang, &sn, &cs);
  float qp = __shfl(qv, lane ^ 32, 64);
  float kp = __shfl(kv, lane ^ 32, 64);
  float qr = (lane < 32) ? (qv * cs + qp * sn) : (-qp * sn + qv * cs);
  float kr = (lane < 32) ? (kv * cs + kp * sn) : (-kp * sn + kv * cs);
  float Kh = expf(ac[h]);
  float sq = qr * qr, sk = kr * kr, sv = vv * vv;
  #pragma unroll
  for (int o = 32; o > 0; o >>= 1) {
    sq += __shfl_xor(sq, o, 64);
    sk += __shfl_xor(sk, o, 64);
    sv += __shfl_xor(sv, o, 64);
  }
  size_t idx = ((size_t)(b * NH + h) * T + t);
  qs[idx * 64 + lane] = qr;
  ks[idx * 64 + lane] = kr;
  vs[idx * 64 + lane] = vv;
  if (lane == 0) {
    q0[idx] = sqrtf(Kh + sq);
    k0[idx] = sqrtf(Kh + sk);
    v0[idx] = sqrtf(Kh + sv);
  }
}

// ---------------- flash Lorentz-distance attention ----------------
__global__ __launch_bounds__(256) void attn_kernel(
    const float* __restrict__ qs, const float* __restrict__ ks, const float* __restrict__ vs,
    const float* __restrict__ q0, const float* __restrict__ k0, const float* __restrict__ v0,
    const float* __restrict__ ac, float* __restrict__ aout) {
  __shared__ float Qs[64][68];
  __shared__ float KPs[64][68];   // K tile during score phase, then P tile
  __shared__ float Vs[64][68];
  __shared__ float q0s[64], k0s[64], v0s[64];

  const int bh = blockIdx.y;
  const int h = bh % NH;
  const int b = bh / NH;
  const int qtile = (int)gridDim.x - 1 - (int)blockIdx.x;  // heavy blocks first
  const int qt0 = qtile * 64;
  const int tid = threadIdx.x;
  const int tx = tid & 15, ty = tid >> 4;
  const int lr = tid >> 4;        // 0..15 (tile-load row base)
  const int lc = (tid & 15) * 4;  // 0..60 (tile-load col)

  const float Kh = expf(ac[h]);
  const float sqrtK = sqrtf(Kh);
  const float invK = 1.0f / Kh;

  {
    #pragma unroll
    for (int rr = 0; rr < 4; ++rr) {
      int row = lr + 16 * rr;
      *(float4*)&Qs[row][lc] =
          *(const float4*)&qs[((size_t)bh * T + qt0 + row) * 64 + lc];
    }
    if (tid < 64) q0s[tid] = q0[(size_t)bh * T + qt0 + tid];
  }

  float m[4], l[4], a0acc[4], acc[4][4];
  #pragma unroll
  for (int ii = 0; ii < 4; ++ii) {
    m[ii] = -__builtin_inff();
    l[ii] = 0.f; a0acc[ii] = 0.f;
    #pragma unroll
    for (int dd = 0; dd < 4; ++dd) acc[ii][dd] = 0.f;
  }

  const int ntiles = qtile + 1;
  for (int kt = 0; kt < ntiles; ++kt) {
    const int j0 = kt * 64;
    __syncthreads();
    {
      #pragma unroll
      for (int rr = 0; rr < 4; ++rr) {
        int row = lr + 16 * rr;
        size_t src = ((size_t)bh * T + j0 + row) * 64 + lc;
        *(float4*)&KPs[row][lc] = *(const float4*)&ks[src];
        *(float4*)&Vs[row][lc] = *(const float4*)&vs[src];
      }
      if (tid < 64) {
        k0s[tid] = k0[(size_t)bh * T + j0 + tid];
        v0s[tid] = v0[(size_t)bh * T + j0 + tid];
      }
    }
    __syncthreads();

    float dot[4][4] = {};
    for (int d4 = 0; d4 < 16; ++d4) {
      float4 qv[4], kv[4];
      #pragma unroll
      for (int ii = 0; ii < 4; ++ii) qv[ii] = *(const float4*)&Qs[4 * ty + ii][4 * d4];
      #pragma unroll
      for (int jj = 0; jj < 4; ++jj) kv[jj] = *(const float4*)&KPs[16 * jj + tx][4 * d4];
      #pragma unroll
      for (int ii = 0; ii < 4; ++ii)
        #pragma unroll
        for (int jj = 0; jj < 4; ++jj)
          dot[ii][jj] += qv[ii].x * kv[jj].x + qv[ii].y * kv[jj].y
                       + qv[ii].z * kv[jj].z + qv[ii].w * kv[jj].w;
    }
    __syncthreads();  // all K reads from KPs done before P overwrites it

    float alpha[4];
    #pragma unroll
    for (int ii = 0; ii < 4; ++ii) {
      const int i = qt0 + 4 * ty + ii;
      const float q0v = q0s[4 * ty + ii];
      float sc[4];
      float rowm = -__builtin_inff();
      #pragma unroll
      for (int jj = 0; jj < 4; ++jj) {
        const int jl = 16 * jj + tx;
        const int j = j0 + jl;
        float cc = (q0v * k0s[jl] - dot[ii][jj]) * invK;
        float u = fmaxf(cc - 1.f, 1e-6f);
        // arccosh(1+u) = log(1 + u + sqrt(u*(u+2)))
        float dist = sqrtK * __logf(1.f + u + sqrtf(u * (u + 2.f)));
        sc[jj] = (j <= i) ? -dist : -__builtin_inff();
        rowm = fmaxf(rowm, sc[jj]);
      }
      rowm = red16_max(rowm);
      const float mnew = fmaxf(m[ii], rowm);
      alpha[ii] = __expf(m[ii] - mnew);
      m[ii] = mnew;
      float ls = 0.f, a0s = 0.f;
      #pragma unroll
      for (int jj = 0; jj < 4; ++jj) {
        const float pv = __expf(sc[jj] - mnew);
        KPs[4 * ty + ii][16 * jj + tx] = pv;
        ls += pv;
        a0s += pv * v0s[16 * jj + tx];
      }
      l[ii] = l[ii] * alpha[ii] + ls;
      a0acc[ii] = a0acc[ii] * alpha[ii] + a0s;
    }
    __syncthreads();  // P visible to all

    #pragma unroll
    for (int ii = 0; ii < 4; ++ii)
      #pragma unroll
      for (int dd = 0; dd < 4; ++dd) acc[ii][dd] *= alpha[ii];

    for (int j4 = 0; j4 < 16; ++j4) {
      float4 vr0 = *(const float4*)&Vs[4 * j4 + 0][4 * tx];
      float4 vr1 = *(const float4*)&Vs[4 * j4 + 1][4 * tx];
      float4 vr2 = *(const float4*)&Vs[4 * j4 + 2][4 * tx];
      float4 vr3 = *(const float4*)&Vs[4 * j4 + 3][4 * tx];
      #pragma unroll
      for (int ii = 0; ii < 4; ++ii) {
        float4 pv = *(const float4*)&KPs[4 * ty + ii][4 * j4];
        acc[ii][0] += pv.x * vr0.x + pv.y * vr1.x + pv.z * vr2.x + pv.w * vr3.x;
        acc[ii][1] += pv.x * vr0.y + pv.y * vr1.y + pv.z * vr2.y + pv.w * vr3.y;
        acc[ii][2] += pv.x * vr0.z + pv.y * vr1.z + pv.z * vr2.z + pv.w * vr3.z;
        acc[ii][3] += pv.x * vr0.w + pv.y * vr1.w + pv.z * vr2.w + pv.w * vr3.w;
      }
    }
  }

  #pragma unroll
  for (int ii = 0; ii < 4; ++ii) {
    float lf = red16_sum(l[ii]);
    float a0f = red16_sum(a0acc[ii]);
    const float invl = 1.f / lf;
    float av[4]; float ssq = 0.f;
    #pragma unroll
    for (int dd = 0; dd < 4; ++dd) { av[dd] = acc[ii][dd] * invl; ssq += av[dd] * av[dd]; }
    ssq = red16_sum(ssq);
    const float a0n = a0f * invl;
    const float nsq = fmaxf(a0n * a0n - ssq, 1e-6f);
    const float scale = sqrtK * rsqrtf(nsq);
    const int i = qt0 + 4 * ty + ii;
    float* orow = aout + (size_t)(b * T + i) * KPA + h * 65;
    #pragma unroll
    for (int dd = 0; dd < 4; ++dd) orow[1 + 4 * tx + dd] = av[dd] * scale;
    if (tx == 0) orow[0] = a0n * scale;
  }
}

// ---------------- exact gelu + project -> bf16 (stride KPB) ----------------
__global__ __launch_bounds__(256) void gelu_project(
    const float* __restrict__ hsrc, const float* __restrict__ curv,
    ushort_t* __restrict__ hp) {
  __shared__ float sm[4];
  const int row = blockIdx.x;
  const int tid = threadIdx.x;
  const float* hr = hsrc + (size_t)row * NEXP;
  float gv[13];
  float ss = 0.f;
  #pragma unroll
  for (int i = 0; i < 13; ++i) {
    int c = tid + 256 * i;
    float xx = (c < HEXP) ? hr[c] : 0.f;
    float gg = 0.5f * xx * (1.f + erff(xx * 0.70710678118654752f));
    gv[i] = gg; ss += gg * gg;
  }
  ss = blk_reduce_sum(ss, sm);
  float tc = sqrtf(expf(curv[0]) + ss);
  ushort_t* orow = hp + (size_t)row * KPB;
  #pragma unroll
  for (int i = 0; i < 13; ++i) {
    int c = tid + 256 * i;
    if (c < HEXP) orow[1 + c] = f2bf(gv[i]);
  }
  if (tid == 0) orow[0] = f2bf(tc);
  if (tid < KPB - (HEXP + 1)) orow[HEXP + 1 + tid] = 0;
}

// ---------------- final projection into d_out (stride 769) ----------------
__global__ __launch_bounds__(256) void final_project(
    const float* __restrict__ x3, const float* __restrict__ curv, float* __restrict__ out) {
  __shared__ float sm[4];
  const int row = blockIdx.x;
  const int tid = threadIdx.x;
  const float* xr = x3 + (size_t)row * NE;
  float v[3]; float ss = 0.f;
  #pragma unroll
  for (int i = 0; i < 3; ++i) { v[i] = xr[tid + 256 * i]; ss += v[i] * v[i]; }
  ss = blk_reduce_sum(ss, sm);
  float tc = sqrtf(expf(curv[0]) + ss);
  float* o = out + (size_t)row * 769;
  #pragma unroll
  for (int i = 0; i < 3; ++i) o[1 + tid + 256 * i] = v[i];
  if (tid == 0) o[0] = tc;
}

// ---------------- launcher ----------------
// ws usage ~131.5 MB (fits the previously-working 169 MB budget).
extern "C" void kernel_launch(void* const* d_in, const int* in_sizes, int n_in,
                              void* d_out, int out_size, void* d_ws, size_t ws_size,
                              hipStream_t stream) {
  (void)in_sizes; (void)n_in; (void)out_size; (void)ws_size;
  const float* x     = (const float*)d_in[0];
  const float* bc    = (const float*)d_in[1];
  const float* mc    = (const float*)d_in[2];
  const float* ac    = (const float*)d_in[3];
  const float* qkvw  = (const float*)d_in[4];
  const float* projw = (const float*)d_in[5];
  const float* projb = (const float*)d_in[6];
  const float* expw  = (const float*)d_in[7];
  const float* expb  = (const float*)d_in[8];
  const float* shrw  = (const float*)d_in[9];
  const float* shrb  = (const float*)d_in[10];
  const float* lng   = (const float*)d_in[11];
  const float* lnb   = (const float*)d_in[12];
  float* out = (float*)d_out;

  // ---- workspace layout ----
  float* aoutf = (float*)d_ws;                               // 4096*800 f32
  float* x2    = aoutf + (size_t)ROWS * KPA;                 // 4096*768 f32
  ushort_t* qkv_wb  = (ushort_t*)(x2 + (size_t)ROWS * NE);   // 2304*800 bf16
  ushort_t* proj_wb = qkv_wb + (size_t)2304 * KPA;           // 768*800
  ushort_t* exp_wb  = proj_wb + (size_t)768 * KPA;           // 3200*800
  ushort_t* shr_wb  = exp_wb + (size_t)NEXP * KPA;           // 768*3104
  ushort_t* lnp_bf  = shr_wb + (size_t)768 * KPB;            // 4096*800
  ushort_t* aout_bf = lnp_bf + (size_t)ROWS * KPA;           // 4096*800
  float* r2 = (float*)(aout_bf + (size_t)ROWS * KPA);
  // r2 union #1: qkv + q/k/v (dead after attention)
  float* qkvb = r2;
  float* qsb  = qkvb + (size_t)ROWS * 2304;
  float* ksb  = qsb + (size_t)48 * T * 64;
  float* vsb  = ksb + (size_t)48 * T * 64;
  float* q0b  = vsb + (size_t)48 * T * 64;
  float* k0b  = q0b + (size_t)48 * T;
  float* v0b  = k0b + (size_t)48 * T;
  // r2 union #2: mlp h (fp32) + projected h (bf16)
  float* hbuf = r2;
  ushort_t* hp_bf = (ushort_t*)(hbuf + (size_t)ROWS * NEXP);

  // ---- weight conversions (ws re-poisoned every call) ----
  cvt_pad<<<(2304 * KPA + 255) / 256, 256, 0, stream>>>(qkv_wb, qkvw, 2304, 769, KPA, 2304);
  cvt_pad<<<(768 * KPA + 255) / 256, 256, 0, stream>>>(proj_wb, projw, 768, 780, KPA, 768);
  cvt_pad<<<(NEXP * KPA + 255) / 256, 256, 0, stream>>>(exp_wb, expw, HEXP, 769, KPA, NEXP);
  cvt_pad<<<(768 * KPB + 255) / 256, 256, 0, stream>>>(shr_wb, shrw, 768, 3076, KPB, 768);
  zero_aout_pad<<<(ROWS + 255) / 256, 256, 0, stream>>>(aoutf);

  // 1. block_norm(lx) -> bf16
  ln_project<<<ROWS, 256, 0, stream>>>(x, lng, lnb, bc, lnp_bf);
  // 2. qkv = ln1p @ qkv_w^T  (bf16 MFMA)
  gemm_bf16<<<dim3(2304 / 128, ROWS / 128), 256, 0, stream>>>(
      lnp_bf, KPA, qkv_wb, KPA, qkvb, 2304, KPA / 32, nullptr, 0, nullptr, 0);
  // 3. rotary + per-head project
  rope_project<<<(ROWS * NH) / 4, 256, 0, stream>>>(qkvb, ac, qsb, ksb, vsb, q0b, k0b, v0b);
  // 4. Lorentz flash attention (fp32)
  attn_kernel<<<dim3(T / 64, 48), 256, 0, stream>>>(qsb, ksb, vsb, q0b, k0b, v0b, ac, aoutf);
  // 4b. convert attn output to bf16
  cvt_pad<<<(ROWS * KPA + 255) / 256, 256, 0, stream>>>(aout_bf, aoutf, ROWS, KPA, KPA, ROWS);
  // 5. attn proj + bias + residual(x) -> x2
  gemm_bf16<<<dim3(768 / 128, ROWS / 128), 256, 0, stream>>>(
      aout_bf, KPA, proj_wb, KPA, x2, NE, KPA / 32, projb, 768, x, NE);
  // 6. block_norm #2 -> bf16
  ln_project<<<ROWS, 256, 0, stream>>>(x2, lng, lnb, bc, lnp_bf);
  // 7. mlp expand + bias
  gemm_bf16<<<dim3(NEXP / 128, ROWS / 128), 256, 0, stream>>>(
      lnp_bf, KPA, exp_wb, KPA, hbuf, NEXP, KPA / 32, expb, HEXP, nullptr, 0);
  // 8. gelu + project -> bf16
  gelu_project<<<ROWS, 256, 0, stream>>>(hbuf, mc, hp_bf);
  // 9. mlp shrink + bias + residual(x2) -> x2 (in-place elementwise safe)
  gemm_bf16<<<dim3(768 / 128, ROWS / 128), 256, 0, stream>>>(
      hp_bf, KPB, shr_wb, KPB, x2, NE, KPB / 32, shrb, 768, x2, NE);
  // 10. final project -> out
  final_project<<<ROWS, 256, 0, stream>>>(x2, bc, out);
}

// Round 4
// 534.308 us; speedup vs baseline: 2.9283x; 1.5977x over previous
//
#include <hip/hip_runtime.h>
#include <cmath>

typedef unsigned short ushort_t;
typedef __attribute__((ext_vector_type(8))) short short8;
typedef __attribute__((ext_vector_type(4))) float floatx4;

// Problem constants
#define NH    12
#define T     1024
#define ROWS  4096      // B*T
#define NE    768
#define KPA   800       // bf16 K-pad for 769/780 (multiple of 32)
#define KPB   3104      // bf16 K-pad for 3076
#define NEXP  3200      // padded expand N (3075 -> 25*128)
#define HEXP  3075

// ---------------- helpers ----------------
__device__ __forceinline__ ushort_t f2bf(float f) {
  union { float f; unsigned u; } v; v.f = f;
  unsigned r = v.u + 0x7fffu + ((v.u >> 16) & 1u);
  return (ushort_t)(r >> 16);
}
__device__ __forceinline__ float bf2f(ushort_t b) {
  union { unsigned u; float f; } v; v.u = ((unsigned)b) << 16;
  return v.f;
}
__device__ __forceinline__ float blk_reduce_sum(float v, float* sm) {
  #pragma unroll
  for (int o = 32; o > 0; o >>= 1) v += __shfl_xor(v, o, 64);
  int lane = threadIdx.x & 63, w = threadIdx.x >> 6;
  __syncthreads();
  if (lane == 0) sm[w] = v;
  __syncthreads();
  return sm[0] + sm[1] + sm[2] + sm[3];
}
__device__ __forceinline__ float red16_sum(float v) {
  #pragma unroll
  for (int o = 1; o < 16; o <<= 1) v += __shfl_xor(v, o, 64);
  return v;
}
__device__ __forceinline__ float red16_max(float v) {
  #pragma unroll
  for (int o = 1; o < 16; o <<= 1) v = fmaxf(v, __shfl_xor(v, o, 64));
  return v;
}

// ---------------- weight pad-convert fp32 -> bf16 ----------------
__global__ void cvt_pad(ushort_t* __restrict__ dst, const float* __restrict__ src,
                        int rows, int srcK, int dstK, int rowsPad) {
  int idx = blockIdx.x * 256 + threadIdx.x;
  int total = rowsPad * dstK;
  if (idx >= total) return;
  int r = idx / dstK, c = idx - r * dstK;
  dst[idx] = (r < rows && c < srcK) ? f2bf(src[(size_t)r * srcK + c]) : (ushort_t)0;
}

__global__ void zero_aout_pad_bf(ushort_t* __restrict__ a) {
  int r = blockIdx.x * 256 + threadIdx.x;
  if (r < ROWS) {
    ushort_t* p = a + (size_t)r * KPA + 780;
    #pragma unroll
    for (int j = 0; j < 20; ++j) p[j] = 0;
  }
}

// ---------------- layernorm + hyperboloid project -> bf16 (stride KPA) -------
__global__ __launch_bounds__(256) void ln_project(
    const float* __restrict__ xin, const float* __restrict__ g,
    const float* __restrict__ bb, const float* __restrict__ curv,
    ushort_t* __restrict__ outp) {
  __shared__ float sm[4];
  const int row = blockIdx.x;
  const int tid = threadIdx.x;
  const float* xr = xin + (size_t)row * NE;
  float xv[3];
  float s = 0.f, ss = 0.f;
  #pragma unroll
  for (int i = 0; i < 3; ++i) {
    xv[i] = xr[tid + 256 * i];
    s += xv[i]; ss += xv[i] * xv[i];
  }
  s = blk_reduce_sum(s, sm);
  ss = blk_reduce_sum(ss, sm);
  float mean = s * (1.f / 768.f);
  float var = ss * (1.f / 768.f) - mean * mean;
  float rstd = rsqrtf(var + 1e-5f);
  float yv[3]; float ys = 0.f;
  #pragma unroll
  for (int i = 0; i < 3; ++i) {
    int c = tid + 256 * i;
    yv[i] = (xv[i] - mean) * rstd * g[c] + bb[c];
    ys += yv[i] * yv[i];
  }
  ys = blk_reduce_sum(ys, sm);
  float tc = sqrtf(expf(curv[0]) + ys);
  ushort_t* orow = outp + (size_t)row * KPA;
  #pragma unroll
  for (int i = 0; i < 3; ++i) orow[1 + tid + 256 * i] = f2bf(yv[i]);
  if (tid == 0) orow[0] = f2bf(tc);
  if (tid < KPA - 769) orow[769 + tid] = 0;
}

// ---------------- bf16 MFMA NT GEMM (m97 structure) --------------------------
__global__ __launch_bounds__(256) void gemm_bf16(
    const ushort_t* __restrict__ A, int lda,
    const ushort_t* __restrict__ W, int ldw,
    float* __restrict__ C, int ldc,
    int nk, const float* __restrict__ bias, int biasN,
    const float* __restrict__ res, int ldres) {
  __shared__ ushort_t As[128 * 32];
  __shared__ ushort_t Bs[128 * 32];
  const int tid = threadIdx.x;
  const int w = tid >> 6, lane = tid & 63;
  const int rowBase = (int)blockIdx.y << 7;
  const int colBase = (int)blockIdx.x << 7;
  const int wm = (w & 1) * 64, wn = (w >> 1) * 64;
  const int lm = lane & 15, quad = lane >> 4;

  floatx4 acc[4][4];
  #pragma unroll
  for (int i = 0; i < 4; ++i)
    #pragma unroll
    for (int j = 0; j < 4; ++j) {
      floatx4 z = {0.f, 0.f, 0.f, 0.f};
      acc[i][j] = z;
    }

  for (int kt = 0; kt < nk; ++kt) {
    __syncthreads();
    #pragma unroll
    for (int j = 0; j < 2; ++j) {
      int c = w * 128 + j * 64 + lane;
      int r = c >> 2, c8 = c & 3;
      const ushort_t* ga = A + (size_t)(rowBase + r) * lda + kt * 32 + c8 * 8;
      const ushort_t* gb = W + (size_t)(colBase + r) * ldw + kt * 32 + c8 * 8;
      __builtin_amdgcn_global_load_lds(
          (const __attribute__((address_space(1))) void*)ga,
          (__attribute__((address_space(3))) void*)&As[(w * 128 + j * 64) * 8],
          16, 0, 0);
      __builtin_amdgcn_global_load_lds(
          (const __attribute__((address_space(1))) void*)gb,
          (__attribute__((address_space(3))) void*)&Bs[(w * 128 + j * 64) * 8],
          16, 0, 0);
    }
    __syncthreads();

    short8 af[4], bfr[4];
    #pragma unroll
    for (int i = 0; i < 4; ++i) {
      af[i]  = *(const short8*)&As[(wm + i * 16 + lm) * 32 + quad * 8];
      bfr[i] = *(const short8*)&Bs[(wn + i * 16 + lm) * 32 + quad * 8];
    }
    #pragma unroll
    for (int i = 0; i < 4; ++i)
      #pragma unroll
      for (int jn = 0; jn < 4; ++jn)
        acc[i][jn] = __builtin_amdgcn_mfma_f32_16x16x32_bf16(
            af[i], bfr[jn], acc[i][jn], 0, 0, 0);
  }

  #pragma unroll
  for (int i = 0; i < 4; ++i) {
    #pragma unroll
    for (int jn = 0; jn < 4; ++jn) {
      const int col = colBase + wn + jn * 16 + lm;
      #pragma unroll
      for (int rg = 0; rg < 4; ++rg) {
        const int row = rowBase + wm + i * 16 + quad * 4 + rg;
        float o = acc[i][jn][rg];
        if (bias) o += (col < biasN) ? bias[col] : 0.f;
        if (res) o += res[(size_t)row * ldres + col];
        C[(size_t)row * ldc + col] = o;
      }
    }
  }
}

// ---------------- rotary + per-head hyperboloid project -> bf16 --------------
__global__ __launch_bounds__(256) void rope_project(
    const float* __restrict__ qkv, const float* __restrict__ ac,
    ushort_t* __restrict__ qb, ushort_t* __restrict__ kb, ushort_t* __restrict__ vtb,
    float* __restrict__ q0, float* __restrict__ k0, float* __restrict__ v0) {
  int gid = blockIdx.x * 4 + (threadIdx.x >> 6);
  int lane = threadIdx.x & 63;
  int h = gid % NH;
  int bt = gid / NH;
  int t = bt & (T - 1);
  int b = bt >> 10;
  size_t base = (size_t)bt * 2304 + h * 64;
  float qv = qkv[base + lane];
  float kv = qkv[base + 768 + lane];
  float vv = qkv[base + 1536 + lane];
  int f = lane & 31;
  float ang = (float)t * powf(10000.f, -(float)f * (1.f / 32.f));
  float sn, cs;
  sincosf(ang, &sn, &cs);
  float qp = __shfl(qv, lane ^ 32, 64);
  float kp = __shfl(kv, lane ^ 32, 64);
  float qr = (lane < 32) ? (qv * cs + qp * sn) : (-qp * sn + qv * cs);
  float kr = (lane < 32) ? (kv * cs + kp * sn) : (-kp * sn + kv * cs);
  float Kh = expf(ac[h]);
  float sq = qr * qr, sk = kr * kr, sv = vv * vv;
  #pragma unroll
  for (int o = 32; o > 0; o >>= 1) {
    sq += __shfl_xor(sq, o, 64);
    sk += __shfl_xor(sk, o, 64);
    sv += __shfl_xor(sv, o, 64);
  }
  size_t idx = ((size_t)(b * NH + h) * T + t);
  qb[idx * 64 + lane] = f2bf(qr);
  kb[idx * 64 + lane] = f2bf(kr);
  // transposed V: vtb[bh][d][t]
  vtb[(size_t)(b * NH + h) * (64 * T) + (size_t)lane * T + t] = f2bf(vv);
  if (lane == 0) {
    q0[idx] = sqrtf(Kh + sq);
    k0[idx] = sqrtf(Kh + sk);
    v0[idx] = sqrtf(Kh + sv);
  }
}

// ---------------- MFMA flash Lorentz-distance attention ----------------------
// one block per (q-tile of 64, b*h); 4 waves, wave w owns Q rows [16w,16w+16)
__global__ __launch_bounds__(256) void attn_kernel(
    const ushort_t* __restrict__ qb, const ushort_t* __restrict__ kb,
    const ushort_t* __restrict__ vtb,
    const float* __restrict__ q0, const float* __restrict__ k0,
    const float* __restrict__ v0,
    const float* __restrict__ ac, ushort_t* __restrict__ aout) {
  __shared__ ushort_t Qs[64 * 64];   // [i][d], chunk-swizzled
  __shared__ ushort_t Ks[64 * 64];   // [j][d], chunk-swizzled
  __shared__ ushort_t Vts[64 * 64];  // [d][j], chunk-swizzled
  __shared__ ushort_t Ps[64 * 72];   // [i][j] bf16, padded

  const int bh = blockIdx.y;
  const int h = bh % NH;
  const int b = bh / NH;
  const int qtile = (int)gridDim.x - 1 - (int)blockIdx.x;  // heavy blocks first
  const int qt0 = qtile * 64;
  const int tid = threadIdx.x;
  const int w = tid >> 6, lane = tid & 63;
  const int lm = lane & 15, quad = lane >> 4;
  const int wm = w * 16;
  const int sw = lm & 7;  // chunk swizzle key for fragment reads

  const float Kh = expf(ac[h]);
  const float sqrtK = sqrtf(Kh);
  const float invK = 1.0f / Kh;

  // Q tile (loaded once; swizzled chunks keep DMA lane-contiguous)
  {
    const ushort_t* qt = qb + ((size_t)bh * T + qt0) * 64;
    #pragma unroll
    for (int j = 0; j < 2; ++j) {
      int e = (j * 4 + w) * 512 + lane * 8;
      int r = e >> 6, chs = (e >> 3) & 7;
      int clog = (chs ^ (r & 7)) * 8;
      __builtin_amdgcn_global_load_lds(
          (const __attribute__((address_space(1))) void*)(qt + r * 64 + clog),
          (__attribute__((address_space(3))) void*)&Qs[(j * 4 + w) * 512],
          16, 0, 0);
    }
  }
  float q0rv[4];
  #pragma unroll
  for (int r = 0; r < 4; ++r)
    q0rv[r] = q0[(size_t)bh * T + qt0 + wm + quad * 4 + r];

  float mrow[4], lsum[4], a0r[4];
  floatx4 oacc[4];
  #pragma unroll
  for (int r = 0; r < 4; ++r) { mrow[r] = -__builtin_inff(); lsum[r] = 0.f; a0r[r] = 0.f; }
  #pragma unroll
  for (int nt = 0; nt < 4; ++nt) { floatx4 z = {0.f,0.f,0.f,0.f}; oacc[nt] = z; }

  const int ntiles = qtile + 1;
  for (int kt = 0; kt < ntiles; ++kt) {
    const int j0 = kt * 64;
    __syncthreads();  // previous iter's LDS reads done
    {
      const ushort_t* ktile = kb + ((size_t)bh * T + j0) * 64;
      const ushort_t* vbh = vtb + (size_t)bh * (64 * T);
      #pragma unroll
      for (int j = 0; j < 2; ++j) {
        int e = (j * 4 + w) * 512 + lane * 8;
        int r = e >> 6, chs = (e >> 3) & 7;
        int clog = (chs ^ (r & 7)) * 8;
        __builtin_amdgcn_global_load_lds(
            (const __attribute__((address_space(1))) void*)(ktile + r * 64 + clog),
            (__attribute__((address_space(3))) void*)&Ks[(j * 4 + w) * 512],
            16, 0, 0);
        __builtin_amdgcn_global_load_lds(
            (const __attribute__((address_space(1))) void*)(vbh + (size_t)r * T + j0 + clog),
            (__attribute__((address_space(3))) void*)&Vts[(j * 4 + w) * 512],
            16, 0, 0);
      }
    }
    float k0v[4], v0v[4];
    #pragma unroll
    for (int jt = 0; jt < 4; ++jt) {
      k0v[jt] = k0[(size_t)bh * T + j0 + jt * 16 + lm];
      v0v[jt] = v0[(size_t)bh * T + j0 + jt * 16 + lm];
    }
    __syncthreads();  // tiles visible (vmcnt drained by barrier semantics)

    // ---- S = Q K^T via MFMA (A: Q rows, B: K rows, both K-contiguous)
    short8 qf0 = *(const short8*)&Qs[(wm + lm) * 64 + ((0 + quad) ^ sw) * 8];
    short8 qf1 = *(const short8*)&Qs[(wm + lm) * 64 + ((4 + quad) ^ sw) * 8];
    floatx4 sacc[4];
    #pragma unroll
    for (int jt = 0; jt < 4; ++jt) {
      const int krow = jt * 16 + lm;
      short8 kf0 = *(const short8*)&Ks[krow * 64 + ((0 + quad) ^ sw) * 8];
      short8 kf1 = *(const short8*)&Ks[krow * 64 + ((4 + quad) ^ sw) * 8];
      floatx4 z = {0.f, 0.f, 0.f, 0.f};
      z = __builtin_amdgcn_mfma_f32_16x16x32_bf16(qf0, kf0, z, 0, 0, 0);
      z = __builtin_amdgcn_mfma_f32_16x16x32_bf16(qf1, kf1, z, 0, 0, 0);
      sacc[jt] = z;
    }

    // ---- score transform + online softmax (C layout: row=quad*4+r, col=jt*16+lm)
    const bool diag = (kt == qtile);
    float alpha[4];
    #pragma unroll
    for (int r = 0; r < 4; ++r) {
      const int i = qt0 + wm + quad * 4 + r;
      float sc[4];
      float rowm = -__builtin_inff();
      #pragma unroll
      for (int jt = 0; jt < 4; ++jt) {
        float c = (q0rv[r] * k0v[jt] - sacc[jt][r]) * invK;
        float u = fmaxf(c - 1.f, 1e-6f);
        float s = -sqrtK * __logf(1.f + u + sqrtf(u * (u + 2.f)));
        if (diag && (j0 + jt * 16 + lm > i)) s = -__builtin_inff();
        sc[jt] = s;
        rowm = fmaxf(rowm, s);
      }
      rowm = red16_max(rowm);
      const float mnew = fmaxf(mrow[r], rowm);
      alpha[r] = __expf(mrow[r] - mnew);
      mrow[r] = mnew;
      float ls = 0.f, a0s = 0.f;
      #pragma unroll
      for (int jt = 0; jt < 4; ++jt) {
        float p = __expf(sc[jt] - mnew);
        ushort_t pb = f2bf(p);
        Ps[(wm + quad * 4 + r) * 72 + jt * 16 + lm] = pb;
        float pf = bf2f(pb);  // use rounded p for l/a0 too (ratio consistency)
        ls += pf;
        a0s += pf * v0v[jt];
      }
      lsum[r] = lsum[r] * alpha[r] + ls;
      a0r[r]  = a0r[r]  * alpha[r] + a0s;
    }

    // ---- O += P V via MFMA (A: P rows from LDS; B: Vt rows, K-contiguous)
    #pragma unroll
    for (int nt = 0; nt < 4; ++nt)
      #pragma unroll
      for (int r = 0; r < 4; ++r) oacc[nt][r] *= alpha[r];
    short8 pf0 = *(const short8*)&Ps[(wm + lm) * 72 + quad * 8];
    short8 pf1 = *(const short8*)&Ps[(wm + lm) * 72 + 32 + quad * 8];
    #pragma unroll
    for (int nt = 0; nt < 4; ++nt) {
      const int vrow = nt * 16 + lm;
      short8 vf0 = *(const short8*)&Vts[vrow * 64 + ((0 + quad) ^ sw) * 8];
      short8 vf1 = *(const short8*)&Vts[vrow * 64 + ((4 + quad) ^ sw) * 8];
      oacc[nt] = __builtin_amdgcn_mfma_f32_16x16x32_bf16(pf0, vf0, oacc[nt], 0, 0, 0);
      oacc[nt] = __builtin_amdgcn_mfma_f32_16x16x32_bf16(pf1, vf1, oacc[nt], 0, 0, 0);
    }
  }

  // ---- epilogue: normalize, Lorentz-rescale, write bf16 into padded layout
  #pragma unroll
  for (int r = 0; r < 4; ++r) {
    float lf = red16_sum(lsum[r]);
    float a0f = red16_sum(a0r[r]);
    const float invl = 1.f / lf;
    float av[4]; float ssq = 0.f;
    #pragma unroll
    for (int nt = 0; nt < 4; ++nt) { av[nt] = oacc[nt][r] * invl; ssq += av[nt] * av[nt]; }
    ssq = red16_sum(ssq);
    const float a0n = a0f * invl;
    const float nsq = fmaxf(a0n * a0n - ssq, 1e-6f);
    const float scale = sqrtK * rsqrtf(nsq);
    const int i = qt0 + wm + quad * 4 + r;
    ushort_t* orow = aout + (size_t)(b * T + i) * KPA + h * 65;
    #pragma unroll
    for (int nt = 0; nt < 4; ++nt) orow[1 + nt * 16 + lm] = f2bf(av[nt] * scale);
    if (lm == 0) orow[0] = f2bf(a0n * scale);
  }
}

// ---------------- exact gelu + project -> bf16 (stride KPB) ----------------
__global__ __launch_bounds__(256) void gelu_project(
    const float* __restrict__ hsrc, const float* __restrict__ curv,
    ushort_t* __restrict__ hp) {
  __shared__ float sm[4];
  const int row = blockIdx.x;
  const int tid = threadIdx.x;
  const float* hr = hsrc + (size_t)row * NEXP;
  float gv[13];
  float ss = 0.f;
  #pragma unroll
  for (int i = 0; i < 13; ++i) {
    int c = tid + 256 * i;
    float xx = (c < HEXP) ? hr[c] : 0.f;
    float gg = 0.5f * xx * (1.f + erff(xx * 0.70710678118654752f));
    gv[i] = gg; ss += gg * gg;
  }
  ss = blk_reduce_sum(ss, sm);
  float tc = sqrtf(expf(curv[0]) + ss);
  ushort_t* orow = hp + (size_t)row * KPB;
  #pragma unroll
  for (int i = 0; i < 13; ++i) {
    int c = tid + 256 * i;
    if (c < HEXP) orow[1 + c] = f2bf(gv[i]);
  }
  if (tid == 0) orow[0] = f2bf(tc);
  if (tid < KPB - (HEXP + 1)) orow[HEXP + 1 + tid] = 0;
}

// ---------------- final projection into d_out (stride 769) ----------------
__global__ __launch_bounds__(256) void final_project(
    const float* __restrict__ x3, const float* __restrict__ curv, float* __restrict__ out) {
  __shared__ float sm[4];
  const int row = blockIdx.x;
  const int tid = threadIdx.x;
  const float* xr = x3 + (size_t)row * NE;
  float v[3]; float ss = 0.f;
  #pragma unroll
  for (int i = 0; i < 3; ++i) { v[i] = xr[tid + 256 * i]; ss += v[i] * v[i]; }
  ss = blk_reduce_sum(ss, sm);
  float tc = sqrtf(expf(curv[0]) + ss);
  float* o = out + (size_t)row * 769;
  #pragma unroll
  for (int i = 0; i < 3; ++i) o[1 + tid + 256 * i] = v[i];
  if (tid == 0) o[0] = tc;
}

// ---------------- launcher ----------------
extern "C" void kernel_launch(void* const* d_in, const int* in_sizes, int n_in,
                              void* d_out, int out_size, void* d_ws, size_t ws_size,
                              hipStream_t stream) {
  (void)in_sizes; (void)n_in; (void)out_size; (void)ws_size;
  const float* x     = (const float*)d_in[0];
  const float* bc    = (const float*)d_in[1];
  const float* mc    = (const float*)d_in[2];
  const float* ac    = (const float*)d_in[3];
  const float* qkvw  = (const float*)d_in[4];
  const float* projw = (const float*)d_in[5];
  const float* projb = (const float*)d_in[6];
  const float* expw  = (const float*)d_in[7];
  const float* expb  = (const float*)d_in[8];
  const float* shrw  = (const float*)d_in[9];
  const float* shrb  = (const float*)d_in[10];
  const float* lng   = (const float*)d_in[11];
  const float* lnb   = (const float*)d_in[12];
  float* out = (float*)d_out;

  // ---- workspace layout (~112 MB) ----
  float* x2 = (float*)d_ws;                                  // 4096*768 f32
  ushort_t* qkv_wb  = (ushort_t*)(x2 + (size_t)ROWS * NE);   // 2304*800 bf16
  ushort_t* proj_wb = qkv_wb + (size_t)2304 * KPA;           // 768*800
  ushort_t* exp_wb  = proj_wb + (size_t)768 * KPA;           // 3200*800
  ushort_t* shr_wb  = exp_wb + (size_t)NEXP * KPA;           // 768*3104
  ushort_t* lnp_bf  = shr_wb + (size_t)768 * KPB;            // 4096*800
  ushort_t* aout_bf = lnp_bf + (size_t)ROWS * KPA;           // 4096*800
  float* r2 = (float*)(aout_bf + (size_t)ROWS * KPA);
  // r2 union #1: qkv fp32 + bf16 q/k/vt + fp32 time components
  float* qkvb = r2;
  ushort_t* qbb = (ushort_t*)(qkvb + (size_t)ROWS * 2304);
  ushort_t* kbb = qbb + (size_t)48 * T * 64;
  ushort_t* vtb = kbb + (size_t)48 * T * 64;
  float* q0b = (float*)(vtb + (size_t)48 * T * 64);
  float* k0b = q0b + (size_t)48 * T;
  float* v0b = k0b + (size_t)48 * T;
  // r2 union #2: mlp h (fp32) + projected h (bf16)
  float* hbuf = r2;
  ushort_t* hp_bf = (ushort_t*)(hbuf + (size_t)ROWS * NEXP);

  // ---- weight conversions (ws re-poisoned every call) ----
  cvt_pad<<<(2304 * KPA + 255) / 256, 256, 0, stream>>>(qkv_wb, qkvw, 2304, 769, KPA, 2304);
  cvt_pad<<<(768 * KPA + 255) / 256, 256, 0, stream>>>(proj_wb, projw, 768, 780, KPA, 768);
  cvt_pad<<<(NEXP * KPA + 255) / 256, 256, 0, stream>>>(exp_wb, expw, HEXP, 769, KPA, NEXP);
  cvt_pad<<<(768 * KPB + 255) / 256, 256, 0, stream>>>(shr_wb, shrw, 768, 3076, KPB, 768);
  zero_aout_pad_bf<<<(ROWS + 255) / 256, 256, 0, stream>>>(aout_bf);

  // 1. block_norm(lx) -> bf16
  ln_project<<<ROWS, 256, 0, stream>>>(x, lng, lnb, bc, lnp_bf);
  // 2. qkv = ln1p @ qkv_w^T  (bf16 MFMA)
  gemm_bf16<<<dim3(2304 / 128, ROWS / 128), 256, 0, stream>>>(
      lnp_bf, KPA, qkv_wb, KPA, qkvb, 2304, KPA / 32, nullptr, 0, nullptr, 0);
  // 3. rotary + per-head project -> bf16 (V transposed)
  rope_project<<<(ROWS * NH) / 4, 256, 0, stream>>>(qkvb, ac, qbb, kbb, vtb, q0b, k0b, v0b);
  // 4. MFMA Lorentz flash attention -> bf16 padded layout
  attn_kernel<<<dim3(T / 64, 48), 256, 0, stream>>>(qbb, kbb, vtb, q0b, k0b, v0b, ac, aout_bf);
  // 5. attn proj + bias + residual(x) -> x2
  gemm_bf16<<<dim3(768 / 128, ROWS / 128), 256, 0, stream>>>(
      aout_bf, KPA, proj_wb, KPA, x2, NE, KPA / 32, projb, 768, x, NE);
  // 6. block_norm #2 -> bf16
  ln_project<<<ROWS, 256, 0, stream>>>(x2, lng, lnb, bc, lnp_bf);
  // 7. mlp expand + bias
  gemm_bf16<<<dim3(NEXP / 128, ROWS / 128), 256, 0, stream>>>(
      lnp_bf, KPA, exp_wb, KPA, hbuf, NEXP, KPA / 32, expb, HEXP, nullptr, 0);
  // 8. gelu + project -> bf16
  gelu_project<<<ROWS, 256, 0, stream>>>(hbuf, mc, hp_bf);
  // 9. mlp shrink + bias + residual(x2) -> x2 (in-place elementwise safe)
  gemm_bf16<<<dim3(768 / 128, ROWS / 128), 256, 0, stream>>>(
      hp_bf, KPB, shr_wb, KPB, x2, NE, KPB / 32, shrb, 768, x2, NE);
  // 10. final project -> out
  final_project<<<ROWS, 256, 0, stream>>>(x2, bc, out);
}

// Round 5
// 432.946 us; speedup vs baseline: 3.6139x; 1.2341x over previous
//
#include <hip/hip_runtime.h>
#include <cmath>

typedef unsigned short ushort_t;
typedef __attribute__((ext_vector_type(8))) short short8;
typedef __attribute__((ext_vector_type(4))) float floatx4;

// Problem constants
#define NH    12
#define T     1024
#define ROWS  4096      // B*T
#define NE    768
#define KPA   800       // bf16 K-pad for 769/780 (multiple of 32)
#define KPB   3104      // bf16 K-pad for 3076
#define NEXP  3200      // padded expand N (3075 -> 25*128)
#define HEXP  3075

// ---------------- helpers ----------------
__device__ __forceinline__ ushort_t f2bf(float f) {
  union { float f; unsigned u; } v; v.f = f;
  unsigned r = v.u + 0x7fffu + ((v.u >> 16) & 1u);
  return (ushort_t)(r >> 16);
}
__device__ __forceinline__ float bf2f(ushort_t b) {
  union { unsigned u; float f; } v; v.u = ((unsigned)b) << 16;
  return v.f;
}
__device__ __forceinline__ float blk_reduce_sum(float v, float* sm) {
  #pragma unroll
  for (int o = 32; o > 0; o >>= 1) v += __shfl_xor(v, o, 64);
  int lane = threadIdx.x & 63, w = threadIdx.x >> 6;
  __syncthreads();
  if (lane == 0) sm[w] = v;
  __syncthreads();
  return sm[0] + sm[1] + sm[2] + sm[3];
}
__device__ __forceinline__ float red16_sum(float v) {
  #pragma unroll
  for (int o = 1; o < 16; o <<= 1) v += __shfl_xor(v, o, 64);
  return v;
}
__device__ __forceinline__ float red16_max(float v) {
  #pragma unroll
  for (int o = 1; o < 16; o <<= 1) v = fmaxf(v, __shfl_xor(v, o, 64));
  return v;
}

// ---------------- weight pad-convert fp32 -> bf16 ----------------
__global__ void cvt_pad(ushort_t* __restrict__ dst, const float* __restrict__ src,
                        int rows, int srcK, int dstK, int rowsPad) {
  int idx = blockIdx.x * 256 + threadIdx.x;
  int total = rowsPad * dstK;
  if (idx >= total) return;
  int r = idx / dstK, c = idx - r * dstK;
  dst[idx] = (r < rows && c < srcK) ? f2bf(src[(size_t)r * srcK + c]) : (ushort_t)0;
}

__global__ void zero_aout_pad_bf(ushort_t* __restrict__ a) {
  int r = blockIdx.x * 256 + threadIdx.x;
  if (r < ROWS) {
    ushort_t* p = a + (size_t)r * KPA + 780;
    #pragma unroll
    for (int j = 0; j < 20; ++j) p[j] = 0;
  }
}

// ---------------- layernorm + hyperboloid project -> bf16 (stride KPA) -------
__global__ __launch_bounds__(256) void ln_project(
    const float* __restrict__ xin, const float* __restrict__ g,
    const float* __restrict__ bb, const float* __restrict__ curv,
    ushort_t* __restrict__ outp) {
  __shared__ float sm[4];
  const int row = blockIdx.x;
  const int tid = threadIdx.x;
  const float* xr = xin + (size_t)row * NE;
  float xv[3];
  float s = 0.f, ss = 0.f;
  #pragma unroll
  for (int i = 0; i < 3; ++i) {
    xv[i] = xr[tid + 256 * i];
    s += xv[i]; ss += xv[i] * xv[i];
  }
  s = blk_reduce_sum(s, sm);
  ss = blk_reduce_sum(ss, sm);
  float mean = s * (1.f / 768.f);
  float var = ss * (1.f / 768.f) - mean * mean;
  float rstd = rsqrtf(var + 1e-5f);
  float yv[3]; float ys = 0.f;
  #pragma unroll
  for (int i = 0; i < 3; ++i) {
    int c = tid + 256 * i;
    yv[i] = (xv[i] - mean) * rstd * g[c] + bb[c];
    ys += yv[i] * yv[i];
  }
  ys = blk_reduce_sum(ys, sm);
  float tc = sqrtf(expf(curv[0]) + ys);
  ushort_t* orow = outp + (size_t)row * KPA;
  #pragma unroll
  for (int i = 0; i < 3; ++i) orow[1 + tid + 256 * i] = f2bf(yv[i]);
  if (tid == 0) orow[0] = f2bf(tc);
  if (tid < KPA - 769) orow[769 + tid] = 0;
}

// ---------------- bf16 MFMA NT GEMM, swizzled LDS, optional split-K ----------
// outMode (gridDim.z==1): 0 = fp32 C (+bias,+res), 1 = bf16 C (+bias)
// gridDim.z>1: fp32 partials to Cp[z][ROWS][ldc], no bias/res.
__global__ __launch_bounds__(256) void gemm_bf16(
    const ushort_t* __restrict__ A, int lda,
    const ushort_t* __restrict__ W, int ldw,
    void* __restrict__ Cout, int ldc,
    int nkTot, int cpt,
    const float* __restrict__ bias, int biasN,
    const float* __restrict__ res, int ldres,
    int outMode, float* __restrict__ Cp) {
  __shared__ ushort_t As[128 * 32];
  __shared__ ushort_t Bs[128 * 32];
  const int tid = threadIdx.x;
  const int w = tid >> 6, lane = tid & 63;
  const int rowBase = (int)blockIdx.y << 7;
  const int colBase = (int)blockIdx.x << 7;
  const int wm = (w & 1) * 64, wn = (w >> 1) * 64;
  const int lm = lane & 15, quad = lane >> 4;
  // fragment-read chunk swizzle: position = quad ^ ((row>>1)&3); row base mult of 16
  const int qp = quad ^ ((lm >> 1) & 3);

  floatx4 acc[4][4];
  #pragma unroll
  for (int i = 0; i < 4; ++i)
    #pragma unroll
    for (int j = 0; j < 4; ++j) {
      floatx4 z = {0.f, 0.f, 0.f, 0.f};
      acc[i][j] = z;
    }

  const int kt0 = (int)blockIdx.z * cpt;
  const int kt1 = min(nkTot, kt0 + cpt);
  for (int kt = kt0; kt < kt1; ++kt) {
    __syncthreads();
    #pragma unroll
    for (int j = 0; j < 2; ++j) {
      int p = w * 128 + j * 64 + lane;       // LDS chunk position
      int r = p >> 2;
      int gq = (p & 3) ^ ((r >> 1) & 3);     // global chunk stored at this position
      const ushort_t* ga = A + (size_t)(rowBase + r) * lda + kt * 32 + gq * 8;
      const ushort_t* gb = W + (size_t)(colBase + r) * ldw + kt * 32 + gq * 8;
      __builtin_amdgcn_global_load_lds(
          (const __attribute__((address_space(1))) void*)ga,
          (__attribute__((address_space(3))) void*)&As[(w * 128 + j * 64) * 8],
          16, 0, 0);
      __builtin_amdgcn_global_load_lds(
          (const __attribute__((address_space(1))) void*)gb,
          (__attribute__((address_space(3))) void*)&Bs[(w * 128 + j * 64) * 8],
          16, 0, 0);
    }
    __syncthreads();

    short8 af[4], bfr[4];
    #pragma unroll
    for (int i = 0; i < 4; ++i) {
      af[i]  = *(const short8*)&As[(wm + i * 16 + lm) * 32 + qp * 8];
      bfr[i] = *(const short8*)&Bs[(wn + i * 16 + lm) * 32 + qp * 8];
    }
    #pragma unroll
    for (int i = 0; i < 4; ++i)
      #pragma unroll
      for (int jn = 0; jn < 4; ++jn)
        acc[i][jn] = __builtin_amdgcn_mfma_f32_16x16x32_bf16(
            af[i], bfr[jn], acc[i][jn], 0, 0, 0);
  }

  if (gridDim.z > 1) {
    float* dst = Cp + (size_t)blockIdx.z * ROWS * ldc;
    #pragma unroll
    for (int i = 0; i < 4; ++i)
      #pragma unroll
      for (int jn = 0; jn < 4; ++jn) {
        const int col = colBase + wn + jn * 16 + lm;
        #pragma unroll
        for (int rg = 0; rg < 4; ++rg) {
          const int row = rowBase + wm + i * 16 + quad * 4 + rg;
          dst[(size_t)row * ldc + col] = acc[i][jn][rg];
        }
      }
  } else if (outMode == 1) {
    ushort_t* C = (ushort_t*)Cout;
    #pragma unroll
    for (int i = 0; i < 4; ++i)
      #pragma unroll
      for (int jn = 0; jn < 4; ++jn) {
        const int col = colBase + wn + jn * 16 + lm;
        const float bv = bias ? ((col < biasN) ? bias[col] : 0.f) : 0.f;
        #pragma unroll
        for (int rg = 0; rg < 4; ++rg) {
          const int row = rowBase + wm + i * 16 + quad * 4 + rg;
          C[(size_t)row * ldc + col] = f2bf(acc[i][jn][rg] + bv);
        }
      }
  } else {
    float* C = (float*)Cout;
    #pragma unroll
    for (int i = 0; i < 4; ++i)
      #pragma unroll
      for (int jn = 0; jn < 4; ++jn) {
        const int col = colBase + wn + jn * 16 + lm;
        const float bv = bias ? ((col < biasN) ? bias[col] : 0.f) : 0.f;
        #pragma unroll
        for (int rg = 0; rg < 4; ++rg) {
          const int row = rowBase + wm + i * 16 + quad * 4 + rg;
          float o = acc[i][jn][rg] + bv;
          if (res) o += res[(size_t)row * ldres + col];
          C[(size_t)row * ldc + col] = o;
        }
      }
  }
}

// ---------------- split-K reduce: out = sum partials + bias + res ------------
__global__ __launch_bounds__(256) void reduce_split(
    const float* __restrict__ Cp, int nsplit,
    const float* __restrict__ bias, const float* __restrict__ res,
    float* __restrict__ outp) {
  int idx = blockIdx.x * 256 + threadIdx.x;   // float4 index
  const int n4 = ROWS * NE / 4;
  if (idx >= n4) return;
  float4 s = ((const float4*)Cp)[idx];
  for (int sp = 1; sp < nsplit; ++sp) {
    float4 t = ((const float4*)(Cp + (size_t)sp * ROWS * NE))[idx];
    s.x += t.x; s.y += t.y; s.z += t.z; s.w += t.w;
  }
  float4 bv = *(const float4*)&bias[(idx * 4) % NE];
  float4 rv = ((const float4*)res)[idx];
  s.x += bv.x + rv.x; s.y += bv.y + rv.y;
  s.z += bv.z + rv.z; s.w += bv.w + rv.w;
  ((float4*)outp)[idx] = s;
}

// ---------------- rotary + per-head hyperboloid project -> bf16 --------------
__global__ __launch_bounds__(256) void rope_project(
    const float* __restrict__ qkv, const float* __restrict__ ac,
    ushort_t* __restrict__ qb, ushort_t* __restrict__ kb, ushort_t* __restrict__ vtb,
    float* __restrict__ q0, float* __restrict__ k0, float* __restrict__ v0) {
  int gid = blockIdx.x * 4 + (threadIdx.x >> 6);
  int lane = threadIdx.x & 63;
  int h = gid % NH;
  int bt = gid / NH;
  int t = bt & (T - 1);
  int b = bt >> 10;
  size_t base = (size_t)bt * 2304 + h * 64;
  float qv = qkv[base + lane];
  float kv = qkv[base + 768 + lane];
  float vv = qkv[base + 1536 + lane];
  int f = lane & 31;
  float ang = (float)t * powf(10000.f, -(float)f * (1.f / 32.f));
  float sn, cs;
  sincosf(ang, &sn, &cs);
  float qp = __shfl(qv, lane ^ 32, 64);
  float kp = __shfl(kv, lane ^ 32, 64);
  float qr = (lane < 32) ? (qv * cs + qp * sn) : (-qp * sn + qv * cs);
  float kr = (lane < 32) ? (kv * cs + kp * sn) : (-kp * sn + kv * cs);
  float Kh = expf(ac[h]);
  float sq = qr * qr, sk = kr * kr, sv = vv * vv;
  #pragma unroll
  for (int o = 32; o > 0; o >>= 1) {
    sq += __shfl_xor(sq, o, 64);
    sk += __shfl_xor(sk, o, 64);
    sv += __shfl_xor(sv, o, 64);
  }
  size_t idx = ((size_t)(b * NH + h) * T + t);
  qb[idx * 64 + lane] = f2bf(qr);
  kb[idx * 64 + lane] = f2bf(kr);
  vtb[(size_t)(b * NH + h) * (64 * T) + (size_t)lane * T + t] = f2bf(vv);
  if (lane == 0) {
    q0[idx] = sqrtf(Kh + sq);
    k0[idx] = sqrtf(Kh + sk);
    v0[idx] = sqrtf(Kh + sv);
  }
}

// ---------------- MFMA flash Lorentz-distance attention ----------------------
__global__ __launch_bounds__(256) void attn_kernel(
    const ushort_t* __restrict__ qb, const ushort_t* __restrict__ kb,
    const ushort_t* __restrict__ vtb,
    const float* __restrict__ q0, const float* __restrict__ k0,
    const float* __restrict__ v0,
    const float* __restrict__ ac, ushort_t* __restrict__ aout) {
  __shared__ ushort_t Qs[64 * 64];   // [i][d], chunk-swizzled
  __shared__ ushort_t Ks[64 * 64];   // [j][d], chunk-swizzled
  __shared__ ushort_t Vts[64 * 64];  // [d][j], chunk-swizzled
  __shared__ ushort_t Ps[64 * 72];   // [i][j] bf16, padded

  const int bh = blockIdx.y;
  const int h = bh % NH;
  const int b = bh / NH;
  const int qtile = (int)gridDim.x - 1 - (int)blockIdx.x;  // heavy blocks first
  const int qt0 = qtile * 64;
  const int tid = threadIdx.x;
  const int w = tid >> 6, lane = tid & 63;
  const int lm = lane & 15, quad = lane >> 4;
  const int wm = w * 16;
  const int sw = lm & 7;  // chunk swizzle key for fragment reads

  const float Kh = expf(ac[h]);
  const float sqrtK = sqrtf(Kh);
  const float invK = 1.0f / Kh;

  {
    const ushort_t* qt = qb + ((size_t)bh * T + qt0) * 64;
    #pragma unroll
    for (int j = 0; j < 2; ++j) {
      int e = (j * 4 + w) * 512 + lane * 8;
      int r = e >> 6, chs = (e >> 3) & 7;
      int clog = (chs ^ (r & 7)) * 8;
      __builtin_amdgcn_global_load_lds(
          (const __attribute__((address_space(1))) void*)(qt + r * 64 + clog),
          (__attribute__((address_space(3))) void*)&Qs[(j * 4 + w) * 512],
          16, 0, 0);
    }
  }
  float q0rv[4];
  #pragma unroll
  for (int r = 0; r < 4; ++r)
    q0rv[r] = q0[(size_t)bh * T + qt0 + wm + quad * 4 + r];

  float mrow[4], lsum[4], a0r[4];
  floatx4 oacc[4];
  #pragma unroll
  for (int r = 0; r < 4; ++r) { mrow[r] = -__builtin_inff(); lsum[r] = 0.f; a0r[r] = 0.f; }
  #pragma unroll
  for (int nt = 0; nt < 4; ++nt) { floatx4 z = {0.f,0.f,0.f,0.f}; oacc[nt] = z; }

  const int ntiles = qtile + 1;
  for (int kt = 0; kt < ntiles; ++kt) {
    const int j0 = kt * 64;
    __syncthreads();
    {
      const ushort_t* ktile = kb + ((size_t)bh * T + j0) * 64;
      const ushort_t* vbh = vtb + (size_t)bh * (64 * T);
      #pragma unroll
      for (int j = 0; j < 2; ++j) {
        int e = (j * 4 + w) * 512 + lane * 8;
        int r = e >> 6, chs = (e >> 3) & 7;
        int clog = (chs ^ (r & 7)) * 8;
        __builtin_amdgcn_global_load_lds(
            (const __attribute__((address_space(1))) void*)(ktile + r * 64 + clog),
            (__attribute__((address_space(3))) void*)&Ks[(j * 4 + w) * 512],
            16, 0, 0);
        __builtin_amdgcn_global_load_lds(
            (const __attribute__((address_space(1))) void*)(vbh + (size_t)r * T + j0 + clog),
            (__attribute__((address_space(3))) void*)&Vts[(j * 4 + w) * 512],
            16, 0, 0);
      }
    }
    float k0v[4], v0v[4];
    #pragma unroll
    for (int jt = 0; jt < 4; ++jt) {
      k0v[jt] = k0[(size_t)bh * T + j0 + jt * 16 + lm];
      v0v[jt] = v0[(size_t)bh * T + j0 + jt * 16 + lm];
    }
    __syncthreads();

    short8 qf0 = *(const short8*)&Qs[(wm + lm) * 64 + ((0 + quad) ^ sw) * 8];
    short8 qf1 = *(const short8*)&Qs[(wm + lm) * 64 + ((4 + quad) ^ sw) * 8];
    floatx4 sacc[4];
    #pragma unroll
    for (int jt = 0; jt < 4; ++jt) {
      const int krow = jt * 16 + lm;
      short8 kf0 = *(const short8*)&Ks[krow * 64 + ((0 + quad) ^ sw) * 8];
      short8 kf1 = *(const short8*)&Ks[krow * 64 + ((4 + quad) ^ sw) * 8];
      floatx4 z = {0.f, 0.f, 0.f, 0.f};
      z = __builtin_amdgcn_mfma_f32_16x16x32_bf16(qf0, kf0, z, 0, 0, 0);
      z = __builtin_amdgcn_mfma_f32_16x16x32_bf16(qf1, kf1, z, 0, 0, 0);
      sacc[jt] = z;
    }

    const bool diag = (kt == qtile);
    float alpha[4];
    #pragma unroll
    for (int r = 0; r < 4; ++r) {
      const int i = qt0 + wm + quad * 4 + r;
      float sc[4];
      float rowm = -__builtin_inff();
      #pragma unroll
      for (int jt = 0; jt < 4; ++jt) {
        float c = (q0rv[r] * k0v[jt] - sacc[jt][r]) * invK;
        float u = fmaxf(c - 1.f, 1e-6f);
        float s = -sqrtK * __logf(1.f + u + sqrtf(u * (u + 2.f)));
        if (diag && (j0 + jt * 16 + lm > i)) s = -__builtin_inff();
        sc[jt] = s;
        rowm = fmaxf(rowm, s);
      }
      rowm = red16_max(rowm);
      const float mnew = fmaxf(mrow[r], rowm);
      alpha[r] = __expf(mrow[r] - mnew);
      mrow[r] = mnew;
      float ls = 0.f, a0s = 0.f;
      #pragma unroll
      for (int jt = 0; jt < 4; ++jt) {
        float p = __expf(sc[jt] - mnew);
        ushort_t pb = f2bf(p);
        Ps[(wm + quad * 4 + r) * 72 + jt * 16 + lm] = pb;
        float pf = bf2f(pb);
        ls += pf;
        a0s += pf * v0v[jt];
      }
      lsum[r] = lsum[r] * alpha[r] + ls;
      a0r[r]  = a0r[r]  * alpha[r] + a0s;
    }

    #pragma unroll
    for (int nt = 0; nt < 4; ++nt)
      #pragma unroll
      for (int r = 0; r < 4; ++r) oacc[nt][r] *= alpha[r];
    short8 pf0 = *(const short8*)&Ps[(wm + lm) * 72 + quad * 8];
    short8 pf1 = *(const short8*)&Ps[(wm + lm) * 72 + 32 + quad * 8];
    #pragma unroll
    for (int nt = 0; nt < 4; ++nt) {
      const int vrow = nt * 16 + lm;
      short8 vf0 = *(const short8*)&Vts[vrow * 64 + ((0 + quad) ^ sw) * 8];
      short8 vf1 = *(const short8*)&Vts[vrow * 64 + ((4 + quad) ^ sw) * 8];
      oacc[nt] = __builtin_amdgcn_mfma_f32_16x16x32_bf16(pf0, vf0, oacc[nt], 0, 0, 0);
      oacc[nt] = __builtin_amdgcn_mfma_f32_16x16x32_bf16(pf1, vf1, oacc[nt], 0, 0, 0);
    }
  }

  #pragma unroll
  for (int r = 0; r < 4; ++r) {
    float lf = red16_sum(lsum[r]);
    float a0f = red16_sum(a0r[r]);
    const float invl = 1.f / lf;
    float av[4]; float ssq = 0.f;
    #pragma unroll
    for (int nt = 0; nt < 4; ++nt) { av[nt] = oacc[nt][r] * invl; ssq += av[nt] * av[nt]; }
    ssq = red16_sum(ssq);
    const float a0n = a0f * invl;
    const float nsq = fmaxf(a0n * a0n - ssq, 1e-6f);
    const float scale = sqrtK * rsqrtf(nsq);
    const int i = qt0 + wm + quad * 4 + r;
    ushort_t* orow = aout + (size_t)(b * T + i) * KPA + h * 65;
    #pragma unroll
    for (int nt = 0; nt < 4; ++nt) orow[1 + nt * 16 + lm] = f2bf(av[nt] * scale);
    if (lm == 0) orow[0] = f2bf(a0n * scale);
  }
}

// ---------------- exact gelu + project: bf16 in (stride NEXP) -> bf16 --------
__global__ __launch_bounds__(256) void gelu_project(
    const ushort_t* __restrict__ hsrc, const float* __restrict__ curv,
    ushort_t* __restrict__ hp) {
  __shared__ float sm[4];
  const int row = blockIdx.x;
  const int tid = threadIdx.x;
  const ushort_t* hr = hsrc + (size_t)row * NEXP;
  float gv[13];
  float ss = 0.f;
  #pragma unroll
  for (int i = 0; i < 13; ++i) {
    int c = tid + 256 * i;
    float xx = (c < HEXP) ? bf2f(hr[c]) : 0.f;
    float gg = 0.5f * xx * (1.f + erff(xx * 0.70710678118654752f));
    gv[i] = gg; ss += gg * gg;
  }
  ss = blk_reduce_sum(ss, sm);
  float tc = sqrtf(expf(curv[0]) + ss);
  ushort_t* orow = hp + (size_t)row * KPB;
  #pragma unroll
  for (int i = 0; i < 13; ++i) {
    int c = tid + 256 * i;
    if (c < HEXP) orow[1 + c] = f2bf(gv[i]);
  }
  if (tid == 0) orow[0] = f2bf(tc);
  if (tid < KPB - (HEXP + 1)) orow[HEXP + 1 + tid] = 0;
}

// ---------------- final projection into d_out (stride 769) ----------------
__global__ __launch_bounds__(256) void final_project(
    const float* __restrict__ x3, const float* __restrict__ curv, float* __restrict__ out) {
  __shared__ float sm[4];
  const int row = blockIdx.x;
  const int tid = threadIdx.x;
  const float* xr = x3 + (size_t)row * NE;
  float v[3]; float ss = 0.f;
  #pragma unroll
  for (int i = 0; i < 3; ++i) { v[i] = xr[tid + 256 * i]; ss += v[i] * v[i]; }
  ss = blk_reduce_sum(ss, sm);
  float tc = sqrtf(expf(curv[0]) + ss);
  float* o = out + (size_t)row * 769;
  #pragma unroll
  for (int i = 0; i < 3; ++i) o[1 + tid + 256 * i] = v[i];
  if (tid == 0) o[0] = tc;
}

// ---------------- launcher ----------------
extern "C" void kernel_launch(void* const* d_in, const int* in_sizes, int n_in,
                              void* d_out, int out_size, void* d_ws, size_t ws_size,
                              hipStream_t stream) {
  (void)in_sizes; (void)n_in; (void)out_size; (void)ws_size;
  const float* x     = (const float*)d_in[0];
  const float* bc    = (const float*)d_in[1];
  const float* mc    = (const float*)d_in[2];
  const float* ac    = (const float*)d_in[3];
  const float* qkvw  = (const float*)d_in[4];
  const float* projw = (const float*)d_in[5];
  const float* projb = (const float*)d_in[6];
  const float* expw  = (const float*)d_in[7];
  const float* expb  = (const float*)d_in[8];
  const float* shrw  = (const float*)d_in[9];
  const float* shrb  = (const float*)d_in[10];
  const float* lng   = (const float*)d_in[11];
  const float* lnb   = (const float*)d_in[12];
  float* out = (float*)d_out;

  // ---- workspace layout (~143 MB worst phase) ----
  float* x2 = (float*)d_ws;                                  // 4096*768 f32
  ushort_t* qkv_wb  = (ushort_t*)(x2 + (size_t)ROWS * NE);   // 2304*800 bf16
  ushort_t* proj_wb = qkv_wb + (size_t)2304 * KPA;           // 768*800
  ushort_t* exp_wb  = proj_wb + (size_t)768 * KPA;           // 3200*800
  ushort_t* shr_wb  = exp_wb + (size_t)NEXP * KPA;           // 768*3104
  ushort_t* lnp_bf  = shr_wb + (size_t)768 * KPB;            // 4096*800
  ushort_t* aout_bf = lnp_bf + (size_t)ROWS * KPA;           // 4096*800
  char* r2 = (char*)(aout_bf + (size_t)ROWS * KPA);
  // r2 union #1 (attn phase): qkv fp32 + bf16 q/k/vt + fp32 time comps
  float* qkvb = (float*)r2;
  ushort_t* qbb = (ushort_t*)(qkvb + (size_t)ROWS * 2304);
  ushort_t* kbb = qbb + (size_t)48 * T * 64;
  ushort_t* vtb = kbb + (size_t)48 * T * 64;
  float* q0b = (float*)(vtb + (size_t)48 * T * 64);
  float* k0b = q0b + (size_t)48 * T;
  float* v0b = k0b + (size_t)48 * T;
  // proj split-K partials (alias front of r2 — qkvb dead by then; qbb.. live
  // region starts at +37.75MB, partials need 25.2MB: no overlap)
  float* ppartP = (float*)r2;                                // 2*ROWS*768 f32
  // r2 union #2 (mlp phase): h bf16 + projected h bf16 + shrink partials
  ushort_t* hbbf = (ushort_t*)r2;                            // ROWS*NEXP bf16
  ushort_t* hp_bf = hbbf + (size_t)ROWS * NEXP;              // ROWS*KPB bf16
  float* ppartS = (float*)(hp_bf + (size_t)ROWS * KPB);      // 4*ROWS*768 f32

  // ---- weight conversions (ws re-poisoned every call) ----
  cvt_pad<<<(2304 * KPA + 255) / 256, 256, 0, stream>>>(qkv_wb, qkvw, 2304, 769, KPA, 2304);
  cvt_pad<<<(768 * KPA + 255) / 256, 256, 0, stream>>>(proj_wb, projw, 768, 780, KPA, 768);
  cvt_pad<<<(NEXP * KPA + 255) / 256, 256, 0, stream>>>(exp_wb, expw, HEXP, 769, KPA, NEXP);
  cvt_pad<<<(768 * KPB + 255) / 256, 256, 0, stream>>>(shr_wb, shrw, 768, 3076, KPB, 768);
  zero_aout_pad_bf<<<(ROWS + 255) / 256, 256, 0, stream>>>(aout_bf);

  // 1. block_norm(lx) -> bf16
  ln_project<<<ROWS, 256, 0, stream>>>(x, lng, lnb, bc, lnp_bf);
  // 2. qkv = ln1p @ qkv_w^T  (direct fp32 out)
  gemm_bf16<<<dim3(2304 / 128, ROWS / 128, 1), 256, 0, stream>>>(
      lnp_bf, KPA, qkv_wb, KPA, qkvb, 2304, KPA / 32, KPA / 32,
      nullptr, 0, nullptr, 0, 0, nullptr);
  // 3. rotary + per-head project -> bf16 (V transposed)
  rope_project<<<(ROWS * NH) / 4, 256, 0, stream>>>(qkvb, ac, qbb, kbb, vtb, q0b, k0b, v0b);
  // 4. MFMA Lorentz flash attention -> bf16 padded layout
  attn_kernel<<<dim3(T / 64, 48), 256, 0, stream>>>(qbb, kbb, vtb, q0b, k0b, v0b, ac, aout_bf);
  // 5. attn proj: split-K=2 partials, then reduce(+bias+res x) -> x2
  gemm_bf16<<<dim3(768 / 128, ROWS / 128, 2), 256, 0, stream>>>(
      aout_bf, KPA, proj_wb, KPA, nullptr, NE, KPA / 32, 13,
      nullptr, 0, nullptr, 0, 0, ppartP);
  reduce_split<<<(ROWS * NE / 4 + 255) / 256, 256, 0, stream>>>(
      ppartP, 2, projb, x, x2);
  // 6. block_norm #2 -> bf16
  ln_project<<<ROWS, 256, 0, stream>>>(x2, lng, lnb, bc, lnp_bf);
  // 7. mlp expand + bias (direct bf16 out)
  gemm_bf16<<<dim3(NEXP / 128, ROWS / 128, 1), 256, 0, stream>>>(
      lnp_bf, KPA, exp_wb, KPA, hbbf, NEXP, KPA / 32, KPA / 32,
      expb, HEXP, nullptr, 0, 1, nullptr);
  // 8. gelu + project -> bf16
  gelu_project<<<ROWS, 256, 0, stream>>>(hbbf, mc, hp_bf);
  // 9. mlp shrink: split-K=4 partials, then reduce(+bias+res x2) -> x2
  gemm_bf16<<<dim3(768 / 128, ROWS / 128, 4), 256, 0, stream>>>(
      hp_bf, KPB, shr_wb, KPB, nullptr, NE, KPB / 32, 25,
      nullptr, 0, nullptr, 0, 0, ppartS);
  reduce_split<<<(ROWS * NE / 4 + 255) / 256, 256, 0, stream>>>(
      ppartS, 4, shrb, x2, x2);
  // 10. final project -> out
  final_project<<<ROWS, 256, 0, stream>>>(x2, bc, out);
}